// Round 11
// baseline (207.997 us; speedup 1.0000x reference)
//
#include <hip/hip_runtime.h>
#include <hip/hip_bf16.h>
#include <cstdint>
#include <cstddef>

// ---------------------------------------------------------------------------
// R11: FUSED conv+fc3. conv_fc3_k: block = 64 rows x 256 cols, 8 waves,
//      per m-tile {conv-produce a2 slice into LDS -> 8 GEMM K-steps};
//      a2p HBM round-trip (147MB write + 79MB read) eliminated. B panel
//      double-buffered global_load_lds with depth-2 prefetch crossing the
//      conv phases. a1/xq windowed (5/7 rows). mgu/cvt unchanged from R8.
// ---------------------------------------------------------------------------

typedef __bf16 bf16x8v __attribute__((ext_vector_type(8)));
typedef float  f32x4   __attribute__((ext_vector_type(4)));
typedef float  f32x2   __attribute__((ext_vector_type(2)));

#define WAVE_FENCE() asm volatile("s_waitcnt lgkmcnt(0)" ::: "memory")
#define WAITV(n) asm volatile("s_waitcnt vmcnt(" #n ")" ::: "memory")

#define FC3_K 3584                  // permuted/padded K (7 Mtiles * 512)
#define A1_PS 24
#define A1_RS (13 * A1_PS)          // 312
#define A1W_ZS (5 * A1_RS)          // 1560: zero slot in 5-row window
#define A1W_SZ 1576                 // 5*312 + 16
#define XQW_RS 20
#define XQW_SZ 140                  // 7 rows * 20

// ---------------- all weight converts in one launch (R8) ----------------
__global__ __launch_bounds__(256) void cvt_all_k(
    const float* __restrict__ fc3w, const float* __restrict__ w2g,
    const float* __restrict__ wih,  const float* __restrict__ whh,
    __hip_bfloat16* __restrict__ w3p, __hip_bfloat16* __restrict__ w2p,
    __hip_bfloat16* __restrict__ wfi, __hip_bfloat16* __restrict__ wfh)
{
    int bid = blockIdx.x;
    if (bid < 3584) {
        int idx = bid * 256 + threadIdx.x;
        int n = idx / FC3_K, kp = idx % FC3_K;
        int mt = kp >> 9, r = kp & 511;
        int fq = r >> 7, col = (r >> 3) & 15, nt = (r >> 2) & 1, j = r & 3;
        int pixel = mt * 16 + fq * 4 + j, oc = nt * 16 + col;
        float v = (pixel < 110) ? fc3w[n * 3520 + oc * 110 + pixel] : 0.f;
        w3p[idx] = __float2bfloat16(v);
    } else if (bid < 3604) {
        int idx = (bid - 3584) * 256 + threadIdx.x;
        if (idx < 5120) {
            int oc = idx / 160, k = idx % 160;
            int koff = k >> 4, ic = k & 15;
            float v = (koff < 9) ? w2g[(oc * 16 + ic) * 9 + koff] : 0.f;
            w2p[idx] = __float2bfloat16(v);
        }
    } else if (bid < 3860) {
        int idx = (bid - 3604) * 256 + threadIdx.x;   // < 65536
        int e = idx & 7, lane = (idx >> 3) & 63, hl = (idx >> 9) & 1;
        int kt = (idx >> 10) & 7, nt = (idx >> 13) & 7;
        int gate = nt * 16 + (lane & 15);
        int k = kt * 32 + (lane >> 4) * 8 + e;
        float v = wih[gate * 256 + k];
        __hip_bfloat16 hi = __float2bfloat16(v);
        wfi[idx] = hl ? __float2bfloat16(v - __bfloat162float(hi)) : hi;
    } else {
        int idx = (bid - 3860) * 256 + threadIdx.x;   // < 16384
        int e = idx & 7, lane = (idx >> 3) & 63, hl = (idx >> 9) & 1;
        int kt = (idx >> 10) & 1, nt = (idx >> 11) & 7;
        int gate = nt * 16 + (lane & 15);
        int k = kt * 32 + (lane >> 4) * 8 + e;
        float v = whh[gate * 64 + k];
        __hip_bfloat16 hi = __float2bfloat16(v);
        wfh[idx] = hl ? __float2bfloat16(v - __bfloat162float(hi)) : hi;
    }
}

// ---------------- fused conv1+conv2+fc3 ----------------
// grid 320 blocks x 512 threads (8 waves). Block owns 64 rows (one t) x 256
// cols. Per m-tile: conv-produce a2_s[64][512] (each wave 8 batches serial,
// windowed a1/xq) -> 8 GEMM K-steps (B dbuf, vmcnt(4), 2 barriers/step).
__global__ __launch_bounds__(512, 1) void conv_fc3_k(
    const float* __restrict__ x, const float* __restrict__ w1g,
    const __hip_bfloat16* __restrict__ w2p,
    const __hip_bfloat16* __restrict__ W,   // w3p [256][3584]
    __hip_bfloat16* __restrict__ a3)        // [20480][256]
{
    __shared__ __hip_bfloat16 a2_s[64 * 512];      // 65536 B
    __shared__ __hip_bfloat16 Bs[2 * 256 * 64];    // 65536 B
    __shared__ __hip_bfloat16 a1w_s[8 * A1W_SZ];   // 25216 B
    __shared__ float          xqw_s[8 * XQW_SZ];   //  4480 B

    const int tid  = threadIdx.x;
    const int wv   = tid >> 6, lane = tid & 63;
    const int fr   = lane & 15, fq = lane >> 4;
    const int R0   = blockIdx.x * 64;

    const int a1b = wv * A1W_SZ;
    const int xqb = wv * XQW_SZ;

    // conv lane constants
    const int ocp = lane & 7, rw = lane >> 3;          // rw 0..7
    const int xr0 = lane / 11, c0 = lane - xr0 * 11;   // flat idx lane < 77
    const int idx1 = lane + 64;
    const int xr1 = idx1 / 11, c1 = idx1 - xr1 * 11;   // valid if lane < 13
    const int fqh = fq >> 1, icb = (fq & 1) * 8;

    // hoist conv2 B-fragments + conv1 weights
    bf16x8v bfrag[5][2];
#pragma unroll
    for (int kt = 0; kt < 5; ++kt)
#pragma unroll
        for (int nt = 0; nt < 2; ++nt)
            bfrag[kt][nt] = *(const bf16x8v*)&w2p[(nt * 16 + fr) * 160 + kt * 32 + fq * 8];
    f32x2 w1v[9];
#pragma unroll
    for (int k = 0; k < 9; ++k) {
        w1v[k][0] = w1g[(2 * ocp) * 9 + k];
        w1v[k][1] = w1g[(2 * ocp + 1) * 9 + k];
    }

    // B stage pointers: GLD i stages rows [i*64 + wv*8, +8), pre-swizzled src
    const int swzc = (lane & 7) ^ rw;
    const __hip_bfloat16* gB0 = W + (size_t)(  0 + wv * 8 + rw) * FC3_K + swzc * 8;
    const __hip_bfloat16* gB1 = W + (size_t)( 64 + wv * 8 + rw) * FC3_K + swzc * 8;
    const __hip_bfloat16* gB2 = W + (size_t)(128 + wv * 8 + rw) * FC3_K + swzc * 8;
    const __hip_bfloat16* gB3 = W + (size_t)(192 + wv * 8 + rw) * FC3_K + swzc * 8;
    __hip_bfloat16* ldsB0 = &Bs[  0 * 64 + wv * 512];
    __hip_bfloat16* ldsB1 = &Bs[ 64 * 64 + wv * 512];
    __hip_bfloat16* ldsB2 = &Bs[128 * 64 + wv * 512];
    __hip_bfloat16* ldsB3 = &Bs[192 * 64 + wv * 512];

#define GLD(src, dst, boff)                                                   \
    __builtin_amdgcn_global_load_lds(                                          \
        (const __attribute__((address_space(1))) void*)(src),                  \
        (__attribute__((address_space(3))) void*)((dst) + (boff)), 16, 0, 0)

#define STAGE_B(b)                                                             \
    do {                                                                       \
        GLD(gB0, ldsB0, (b) * 16384); GLD(gB1, ldsB1, (b) * 16384);            \
        GLD(gB2, ldsB2, (b) * 16384); GLD(gB3, ldsB3, (b) * 16384);            \
        gB0 += 64; gB1 += 64; gB2 += 64; gB3 += 64;                            \
    } while (0)

    // zero a1 window (incl. zero slot) and xq window
    bf16x8v z8 = {};
#pragma unroll
    for (int i = 0; i < 4; ++i) {
        int c = lane + i * 64;
        if (c < A1W_SZ / 8) *(bf16x8v*)&a1w_s[a1b + c * 8] = z8;
    }
    {
        float4 zf = {0.f, 0.f, 0.f, 0.f};
        if (lane < XQW_SZ / 4) *(float4*)&xqw_s[xqb + lane * 4] = zf;
    }

    // GEMM lane constants
    const int cA0 = ((0 + fq) ^ (fr & 7)) * 8;
    const int cA1 = ((4 + fq) ^ (fr & 7)) * 8;

    f32x4 acc[4][2];
#pragma unroll
    for (int mi = 0; mi < 4; ++mi)
#pragma unroll
        for (int ni = 0; ni < 2; ++ni)
            acc[mi][ni] = (f32x4){0.f, 0.f, 0.f, 0.f};

    STAGE_B(0);                    // global step 0 -> buf0
    STAGE_B(1);                    // global step 1 -> buf1

    const int h0v[7] = {0, 1, 2, 4, 5, 7, 8};
    const int h1v[7] = {1, 2, 4, 5, 7, 8, 9};

#pragma unroll
    for (int mt = 0; mt < 7; ++mt) {
        const int h0 = h0v[mt], h1 = h1v[mt];
        const int WB = h0 - 1, XB = h0 - 2, P0 = mt * 16;
        (void)h1;

        // mt6: window row 3 = image row 10 (halo) holds stale mt5 data -> zero
        if (mt == 6) {
            if (lane < 39) *(bf16x8v*)&a1w_s[a1b + 3 * A1_RS + lane * 8] = z8;
        }

        // ---- bulk x loads for this wave's 8 batches (window rows) ----
        float q0[8], q1[8];
#pragma unroll
        for (int bi = 0; bi < 8; ++bi) {
            int gr = R0 + wv * 8 + bi;
            const float* xb = x + (size_t)(gr & 2047) * 1100 + (gr >> 11) * 110;
            int ir0 = XB + xr0;
            int ad0 = (ir0 < 0 ? 0 : (ir0 > 9 ? 9 : ir0)) * 11 + c0;
            float v0 = xb[ad0];
            q0[bi] = (ir0 >= 0 && ir0 <= 9) ? v0 : 0.f;
            int ir1 = XB + xr1;
            int ad1 = (ir1 < 0 ? 0 : (ir1 > 9 ? 9 : ir1)) * 11 + (c1 > 10 ? 10 : c1);
            float v1 = xb[ad1];
            q1[bi] = (lane < 13 && ir1 >= 0 && ir1 <= 9) ? v1 : 0.f;
        }

        // ---- per batch: quantize -> conv1 -> conv2 -> a2_s ----
#pragma unroll
        for (int bi = 0; bi < 8; ++bi) {
            {
                float v = fminf(fmaxf(q0[bi], -1.f), 1.f);
                xqw_s[xqb + xr0 * XQW_RS + c0 + 1] = rintf(v * 128.f) * 0.0078125f;
                if (lane < 13) {
                    float u = fminf(fmaxf(q1[bi], -1.f), 1.f);
                    xqw_s[xqb + xr1 * XQW_RS + c1 + 1] = rintf(u * 128.f) * 0.0078125f;
                }
            }
            WAVE_FENCE();

            // conv1: window row rw (image row WB+rw)
            {
                int ir = WB + rw;
                if (rw < 5 && ir >= 0 && ir <= 9) {
                    f32x2 a1acc[11];
#pragma unroll
                    for (int w = 0; w < 11; ++w) a1acc[w] = (f32x2){0.f, 0.f};
#pragma unroll
                    for (int dr = 0; dr < 3; ++dr) {
                        float xr[16];
                        const float* row = &xqw_s[xqb + (rw + dr) * XQW_RS];
#pragma unroll
                        for (int j = 0; j < 4; ++j)
                            *(float4*)&xr[j * 4] = *(const float4*)&row[j * 4];
#pragma unroll
                        for (int dc = 0; dc < 3; ++dc) {
                            f32x2 wv2 = w1v[dr * 3 + dc];
#pragma unroll
                            for (int w = 0; w < 11; ++w)
                                a1acc[w] += wv2 * xr[w + dc];
                        }
                    }
#pragma unroll
                    for (int w = 0; w < 11; ++w) {
                        __hip_bfloat162 pr;
                        pr.x = __float2bfloat16(fminf(fmaxf(a1acc[w][0], 0.f), 1.f));
                        pr.y = __float2bfloat16(fminf(fmaxf(a1acc[w][1], 0.f), 1.f));
                        *(__hip_bfloat162*)&a1w_s[a1b + rw * A1_RS + (w + 1) * A1_PS + 2 * ocp] = pr;
                    }
                }
            }
            WAVE_FENCE();

            // conv2 m-tile -> a2_s row
            {
                int p = P0 + fr; if (p > 109) p = 109;
                int h = p / 11, w = p - h * 11;
                const int bm = a1b + (h - h0) * A1_RS + w * A1_PS;
                const int d0 = fqh * 24 + icb;
                const int d1 = (fqh ? A1_RS : 48) + icb;
                const int d2 = A1_RS + 24 + fqh * 24 + icb;
                const int d3 = 2 * A1_RS + fqh * 24 + icb;
                f32x4 c2a = {0.f, 0.f, 0.f, 0.f}, c2b = {0.f, 0.f, 0.f, 0.f};
                bf16x8v a0 = *(const bf16x8v*)&a1w_s[bm + d0];
                bf16x8v a1 = *(const bf16x8v*)&a1w_s[bm + d1];
                bf16x8v a2 = *(const bf16x8v*)&a1w_s[bm + d2];
                bf16x8v av3 = *(const bf16x8v*)&a1w_s[bm + d3];
                bf16x8v a4 = *(const bf16x8v*)&a1w_s[fqh ? (a1b + A1W_ZS)
                                                         : (bm + 2 * A1_RS + 2 * 24 + icb)];
                c2a = __builtin_amdgcn_mfma_f32_16x16x32_bf16(a0, bfrag[0][0], c2a, 0, 0, 0);
                c2b = __builtin_amdgcn_mfma_f32_16x16x32_bf16(a0, bfrag[0][1], c2b, 0, 0, 0);
                c2a = __builtin_amdgcn_mfma_f32_16x16x32_bf16(a1, bfrag[1][0], c2a, 0, 0, 0);
                c2b = __builtin_amdgcn_mfma_f32_16x16x32_bf16(a1, bfrag[1][1], c2b, 0, 0, 0);
                c2a = __builtin_amdgcn_mfma_f32_16x16x32_bf16(a2, bfrag[2][0], c2a, 0, 0, 0);
                c2b = __builtin_amdgcn_mfma_f32_16x16x32_bf16(a2, bfrag[2][1], c2b, 0, 0, 0);
                c2a = __builtin_amdgcn_mfma_f32_16x16x32_bf16(av3, bfrag[3][0], c2a, 0, 0, 0);
                c2b = __builtin_amdgcn_mfma_f32_16x16x32_bf16(av3, bfrag[3][1], c2b, 0, 0, 0);
                c2a = __builtin_amdgcn_mfma_f32_16x16x32_bf16(a4, bfrag[4][0], c2a, 0, 0, 0);
                c2b = __builtin_amdgcn_mfma_f32_16x16x32_bf16(a4, bfrag[4][1], c2b, 0, 0, 0);

                bf16x8v ov;
#pragma unroll
                for (int j = 0; j < 4; ++j) {
                    bool valid = (P0 + fq * 4 + j) < 110;
                    float v0 = valid ? fminf(fmaxf(c2a[j], 0.f), 1.f) : 0.f;
                    float v1 = valid ? fminf(fmaxf(c2b[j], 0.f), 1.f) : 0.f;
                    ov[j]     = (__bf16)v0;
                    ov[4 + j] = (__bf16)v1;
                }
                const int rowl = wv * 8 + bi;
                *(bf16x8v*)&a2_s[rowl * 512 + (lane >> 3) * 64 +
                                 (((lane & 7) ^ (rowl & 7)) * 8)] = ov;
            }
        }
        WAVE_FENCE();              // a2 writes complete before barrier

        // ---- GEMM: 8 K-steps over a2_s x Bs (R8 2-barrier pattern) ----
#pragma unroll
        for (int kt2 = 0; kt2 < 8; ++kt2) {
            const int s = mt * 8 + kt2;
            if (s == 55) { WAITV(0); } else { WAITV(4); }
            __builtin_amdgcn_s_barrier();
            {
                const int bufo = (kt2 & 1) * 16384;
                const int kb = kt2 * 64;
#pragma unroll
                for (int kk = 0; kk < 2; ++kk) {
                    const int cc = kk ? cA1 : cA0;
                    bf16x8v af[4], bfv[2];
#pragma unroll
                    for (int mi = 0; mi < 4; ++mi)
                        af[mi] = *(const bf16x8v*)&a2_s[(mi * 16 + fr) * 512 + kb + cc];
#pragma unroll
                    for (int ni = 0; ni < 2; ++ni)
                        bfv[ni] = *(const bf16x8v*)&Bs[bufo + (wv * 32 + ni * 16 + fr) * 64 + cc];
#pragma unroll
                    for (int mi = 0; mi < 4; ++mi)
#pragma unroll
                        for (int ni = 0; ni < 2; ++ni)
                            acc[mi][ni] = __builtin_amdgcn_mfma_f32_16x16x32_bf16(
                                af[mi], bfv[ni], acc[mi][ni], 0, 0, 0);
                }
            }
            __builtin_amdgcn_s_barrier();
            if (s + 2 <= 55) STAGE_B(kt2 & 1);
        }
    }

#undef GLD
#undef STAGE_B

    // epilogue: clip -> bf16 a3
#pragma unroll
    for (int mi = 0; mi < 4; ++mi)
#pragma unroll
        for (int ni = 0; ni < 2; ++ni)
#pragma unroll
            for (int j = 0; j < 4; ++j) {
                int row = R0 + mi * 16 + fq * 4 + j;
                int col = wv * 32 + ni * 16 + fr;
                float v = fminf(fmaxf(acc[mi][ni][j], 0.f), 1.f);
                a3[(size_t)row * 256 + col] = __float2bfloat16(v);
            }
}

// ---------------- MGU all steps + fc5, one kernel (R8) ----------------
__global__ __launch_bounds__(256, 1) void mgu_all_k(
    const __hip_bfloat16* __restrict__ a3,  // [10*2048][256]
    const __hip_bfloat16* __restrict__ wfi, const __hip_bfloat16* __restrict__ wfh,
    const float* __restrict__ w5, float* __restrict__ out)
{
    __shared__ __hip_bfloat16 a3_s[16 * 256];
    __shared__ __hip_bfloat16 hq_s[16 * 64];
    __shared__ float hx_s[16 * 64];
    __shared__ float w5_s[7 * 64];

    const int tid = threadIdx.x;
    const int wv  = tid >> 6, lane = tid & 63;
    const int fr  = lane & 15, fq = lane >> 4;
    const int b0  = blockIdx.x * 16;
    const int ntf = wv, ntn = wv + 4;

    bf16x8v wiF[8][2], wiN[8][2], whF[2][2], whN[2][2];
#pragma unroll
    for (int kt = 0; kt < 8; ++kt)
#pragma unroll
        for (int hl = 0; hl < 2; ++hl) {
            wiF[kt][hl] = *(const bf16x8v*)&wfi[(((ntf * 8 + kt) * 2 + hl) * 64 + lane) * 8];
            wiN[kt][hl] = *(const bf16x8v*)&wfi[(((ntn * 8 + kt) * 2 + hl) * 64 + lane) * 8];
        }
#pragma unroll
    for (int kt = 0; kt < 2; ++kt)
#pragma unroll
        for (int hl = 0; hl < 2; ++hl) {
            whF[kt][hl] = *(const bf16x8v*)&wfh[(((ntf * 2 + kt) * 2 + hl) * 64 + lane) * 8];
            whN[kt][hl] = *(const bf16x8v*)&wfh[(((ntn * 2 + kt) * 2 + hl) * 64 + lane) * 8];
        }

    for (int i = tid; i < 16 * 64; i += 256) hx_s[i] = 0.f;
    for (int i = tid; i < 7 * 64; i += 256) w5_s[i] = w5[i];
    __syncthreads();

    for (int t = 0; t < 10; ++t) {
#pragma unroll
        for (int pass = 0; pass < 2; ++pass) {
            int i = pass * 256 + tid;
            int r = i >> 5, cq = i & 31;
            bf16x8v v = *(const bf16x8v*)&a3[((size_t)(t * 2048 + b0 + r)) * 256 + cq * 8];
            *(bf16x8v*)&a3_s[r * 256 + ((cq ^ (r & 7)) * 8)] = v;
        }
#pragma unroll
        for (int pass = 0; pass < 4; ++pass) {
            int i = pass * 256 + tid;
            int r = i >> 6, c = i & 63;
            float v = hx_s[r * 64 + c];
            v = fminf(fmaxf(v, -1.f), 1.f);
            v = rintf(v * 128.f) * 0.0078125f;
            hq_s[r * 64 + (((c >> 3) ^ (r & 7)) << 3) + (c & 7)] = __float2bfloat16(v);
        }
        __syncthreads();

        f32x4 accF  = {0.f, 0.f, 0.f, 0.f};
        f32x4 accNi = {0.f, 0.f, 0.f, 0.f};
        f32x4 accNh = {0.f, 0.f, 0.f, 0.f};
#pragma unroll
        for (int kt = 0; kt < 8; ++kt) {
            bf16x8v a = *(const bf16x8v*)&a3_s[fr * 256 + (((kt * 4 + fq) ^ (fr & 7)) * 8)];
            accF  = __builtin_amdgcn_mfma_f32_16x16x32_bf16(a, wiF[kt][0], accF, 0, 0, 0);
            accF  = __builtin_amdgcn_mfma_f32_16x16x32_bf16(a, wiF[kt][1], accF, 0, 0, 0);
            accNi = __builtin_amdgcn_mfma_f32_16x16x32_bf16(a, wiN[kt][0], accNi, 0, 0, 0);
            accNi = __builtin_amdgcn_mfma_f32_16x16x32_bf16(a, wiN[kt][1], accNi, 0, 0, 0);
        }
#pragma unroll
        for (int kt = 0; kt < 2; ++kt) {
            bf16x8v a = *(const bf16x8v*)&hq_s[fr * 64 + (((kt * 4 + fq) ^ (fr & 7)) * 8)];
            accF  = __builtin_amdgcn_mfma_f32_16x16x32_bf16(a, whF[kt][0], accF, 0, 0, 0);
            accF  = __builtin_amdgcn_mfma_f32_16x16x32_bf16(a, whF[kt][1], accF, 0, 0, 0);
            accNh = __builtin_amdgcn_mfma_f32_16x16x32_bf16(a, whN[kt][0], accNh, 0, 0, 0);
            accNh = __builtin_amdgcn_mfma_f32_16x16x32_bf16(a, whN[kt][1], accNh, 0, 0, 0);
        }

        const int j5 = wv * 16 + fr;
#pragma unroll
        for (int j = 0; j < 4; ++j) {
            int b = fq * 4 + j;
            float f = fminf(fmaxf(0.5f * accF[j] + 0.5f, 0.f), 1.f);
            float n = fminf(fmaxf(accNi[j] + f * accNh[j], -1.f), 1.f);
            float hq = __bfloat162float(
                hq_s[b * 64 + ((((j5) >> 3) ^ (b & 7)) << 3) + (j5 & 7)]);
            hx_s[b * 64 + j5] = (1.f - f) * n + f * hq;
        }
        __syncthreads();
    }

    if (tid < 112) {
        int b = tid / 7, c = tid % 7;
        float acc = 0.f;
#pragma unroll
        for (int k = 0; k < 64; ++k) acc += hx_s[b * 64 + k] * w5_s[c * 64 + k];
        out[(size_t)(b0 + b) * 7 + c] = acc;
    }
}

extern "C" void kernel_launch(void* const* d_in, const int* in_sizes, int n_in,
                              void* d_out, int out_size, void* d_ws, size_t ws_size,
                              hipStream_t stream)
{
    const float* x    = (const float*)d_in[0];
    const float* w1   = (const float*)d_in[1];
    const float* w2   = (const float*)d_in[2];
    const float* fc3w = (const float*)d_in[3];
    const float* wih  = (const float*)d_in[4];
    const float* whh  = (const float*)d_in[5];
    const float* fc5w = (const float*)d_in[6];
    float* out = (float*)d_out;

    char* ws = (char*)d_ws;
    __hip_bfloat16* a3  = (__hip_bfloat16*)ws;                    // 10,485,760
    __hip_bfloat16* w3p = (__hip_bfloat16*)(ws + 10485760);       //  1,835,008
    __hip_bfloat16* w2p = (__hip_bfloat16*)(ws + 12320768);       //     10,240
    __hip_bfloat16* wfi = (__hip_bfloat16*)(ws + 12331008);       //    131,072
    __hip_bfloat16* wfh = (__hip_bfloat16*)(ws + 12462080);       //     32,768

    cvt_all_k<<<3924, 256, 0, stream>>>(fc3w, w2, wih, whh, w3p, w2p, wfi, wfh);
    conv_fc3_k<<<320, 512, 0, stream>>>(x, w1, w2p, w3p, a3);
    mgu_all_k<<<128, 256, 0, stream>>>(a3, wfi, wfh, fc5w, out);
}

// Round 12
// 135.354 us; speedup vs baseline: 1.5367x; 1.5367x over previous
//
#include <hip/hip_runtime.h>
#include <hip/hip_bf16.h>
#include <cstdint>
#include <cstddef>

// ---------------------------------------------------------------------------
// R12: R8 base (cvt_all, conv_all, mgu_all verbatim). fc3 rebuilt as
//      1-wave blocks: wave owns a 64x64 tile (acc 4x4), ZERO barriers
//      (wave-private LDS dbuf sequenced by vmcnt only), grid 1280 = 5
//      blocks/CU balanced, 32KB LDS, setprio around MFMA cluster.
// ---------------------------------------------------------------------------

typedef __bf16 bf16x8v __attribute__((ext_vector_type(8)));
typedef float  f32x4   __attribute__((ext_vector_type(4)));

#define WAVE_FENCE() asm volatile("s_waitcnt lgkmcnt(0)" ::: "memory")
#define WAITV(n) asm volatile("s_waitcnt vmcnt(" #n ")" ::: "memory")

#define A1_PS 24
#define A1_RS (13 * A1_PS)          // 312
#define A1_ZS (12 * A1_RS)          // zero slot
#define A1_BS 3776                  // per-batch elems (7552 B)
#define XQ_RS 20
#define XQ_BS 256

#define FC3_K 3584                  // permuted/padded K (7 Mtiles * 512)

// ---------------- all weight converts in one launch ----------------
__global__ __launch_bounds__(256) void cvt_all_k(
    const float* __restrict__ fc3w, const float* __restrict__ w2g,
    const float* __restrict__ wih,  const float* __restrict__ whh,
    __hip_bfloat16* __restrict__ w3p, __hip_bfloat16* __restrict__ w2p,
    __hip_bfloat16* __restrict__ wfi, __hip_bfloat16* __restrict__ wfh)
{
    int bid = blockIdx.x;
    if (bid < 3584) {
        int idx = bid * 256 + threadIdx.x;
        int n = idx / FC3_K, kp = idx % FC3_K;
        int mt = kp >> 9, r = kp & 511;
        int fq = r >> 7, col = (r >> 3) & 15, nt = (r >> 2) & 1, j = r & 3;
        int pixel = mt * 16 + fq * 4 + j, oc = nt * 16 + col;
        float v = (pixel < 110) ? fc3w[n * 3520 + oc * 110 + pixel] : 0.f;
        w3p[idx] = __float2bfloat16(v);
    } else if (bid < 3604) {
        int idx = (bid - 3584) * 256 + threadIdx.x;
        if (idx < 5120) {
            int oc = idx / 160, k = idx % 160;
            int koff = k >> 4, ic = k & 15;
            float v = (koff < 9) ? w2g[(oc * 16 + ic) * 9 + koff] : 0.f;
            w2p[idx] = __float2bfloat16(v);
        }
    } else if (bid < 3860) {
        int idx = (bid - 3604) * 256 + threadIdx.x;   // < 65536
        int e = idx & 7, lane = (idx >> 3) & 63, hl = (idx >> 9) & 1;
        int kt = (idx >> 10) & 7, nt = (idx >> 13) & 7;
        int gate = nt * 16 + (lane & 15);
        int k = kt * 32 + (lane >> 4) * 8 + e;
        float v = wih[gate * 256 + k];
        __hip_bfloat16 hi = __float2bfloat16(v);
        wfi[idx] = hl ? __float2bfloat16(v - __bfloat162float(hi)) : hi;
    } else {
        int idx = (bid - 3860) * 256 + threadIdx.x;   // < 16384
        int e = idx & 7, lane = (idx >> 3) & 63, hl = (idx >> 9) & 1;
        int kt = (idx >> 10) & 1, nt = (idx >> 11) & 7;
        int gate = nt * 16 + (lane & 15);
        int k = kt * 32 + (lane >> 4) * 8 + e;
        float v = whh[gate * 64 + k];
        __hip_bfloat16 hi = __float2bfloat16(v);
        wfh[idx] = hl ? __float2bfloat16(v - __bfloat162float(hi)) : hi;
    }
}

// ---------------- all-steps fused quant + conv1 + conv2 (R8) ----------------
__global__ __launch_bounds__(256) void conv_all_k(
    const float* __restrict__ x, const float* __restrict__ w1g,
    const __hip_bfloat16* __restrict__ w2p,
    __hip_bfloat16* __restrict__ a2p)
{
    __shared__ __hip_bfloat16 a1_s[4 * A1_BS];
    __shared__ float xq_s[4 * XQ_BS];

    const int tid  = threadIdx.x;
    const int wv   = tid >> 6, lane = tid & 63;
    const int t    = blockIdx.x >> 9;
    const int b    = (blockIdx.x & 511) * 4 + wv;
    const int ab   = wv * A1_BS;
    const int xb   = wv * XQ_BS;

    const int fr  = lane & 15, fq = lane >> 4;
    const int fqh = fq >> 1,  icb = (fq & 1) * 8;

    bf16x8v bfrag[5][2];
#pragma unroll
    for (int kt = 0; kt < 5; ++kt)
#pragma unroll
        for (int nt = 0; nt < 2; ++nt)
            bfrag[kt][nt] = *(const bf16x8v*)&w2p[(nt * 16 + fr) * 160 + kt * 32 + fq * 8];

    const int ocp = lane & 7, rs = lane >> 3;
    float w1a[9], w1b[9];
#pragma unroll
    for (int k = 0; k < 9; ++k) {
        w1a[k] = w1g[(2 * ocp) * 9 + k];
        w1b[k] = w1g[(2 * ocp + 1) * 9 + k];
    }

    {
        bf16x8v z = {};
#pragma unroll
        for (int i = 0; i < 8; ++i) {
            int c = lane + i * 64;
            if (c < A1_BS / 8) *(bf16x8v*)&a1_s[ab + c * 8] = z;
        }
        float4 zf = {0.f, 0.f, 0.f, 0.f};
        *(float4*)&xq_s[xb + lane * 4] = zf;
    }
    WAVE_FENCE();

#pragma unroll
    for (int pass = 0; pass < 2; ++pass) {
        int p = pass * 64 + lane;
        if (p < 110) {
            float xv = x[(size_t)b * 1100 + t * 110 + p];
            xv = fminf(fmaxf(xv, -1.f), 1.f);
            xv = rintf(xv * 128.f) * 0.0078125f;
            int h = p / 11, w = p - h * 11;
            xq_s[xb + (h + 1) * XQ_RS + (w + 1)] = xv;
        }
    }
    WAVE_FENCE();

#pragma unroll
    for (int pass = 0; pass < 2; ++pass) {
        const int hr = pass == 0 ? rs : rs + 8;
        if (hr < 10) {
            float acc0[11], acc1[11];
#pragma unroll
            for (int w = 0; w < 11; ++w) { acc0[w] = 0.f; acc1[w] = 0.f; }
#pragma unroll
            for (int dr = 0; dr < 3; ++dr) {
                float xr[16];
                const float* row = &xq_s[xb + (hr + dr) * XQ_RS];
#pragma unroll
                for (int j = 0; j < 4; ++j)
                    *(float4*)&xr[j * 4] = *(const float4*)&row[j * 4];
#pragma unroll
                for (int dc = 0; dc < 3; ++dc) {
                    float wa = w1a[dr * 3 + dc], wb = w1b[dr * 3 + dc];
#pragma unroll
                    for (int w = 0; w < 11; ++w) {
                        acc0[w] += xr[w + dc] * wa;
                        acc1[w] += xr[w + dc] * wb;
                    }
                }
            }
#pragma unroll
            for (int w = 0; w < 11; ++w) {
                __hip_bfloat162 pr;
                pr.x = __float2bfloat16(fminf(fmaxf(acc0[w], 0.f), 1.f));
                pr.y = __float2bfloat16(fminf(fmaxf(acc1[w], 0.f), 1.f));
                *(__hip_bfloat162*)&a1_s[ab + (hr + 1) * A1_RS + (w + 1) * A1_PS + 2 * ocp] = pr;
            }
        }
    }
    WAVE_FENCE();

    const int d0 = fqh * 24 + icb;
    const int d1 = (fqh ? 312 : 48) + icb;
    const int d2 = 336 + fqh * 24 + icb;
    const int d3 = 624 + fqh * 24 + icb;

#pragma unroll
    for (int m = 0; m < 7; ++m) {
        int p = m * 16 + fr; if (p > 109) p = 109;
        int h = p / 11, w = p - h * 11;
        const int bm = ab + h * A1_RS + w * A1_PS;
        f32x4 acc0 = {0.f, 0.f, 0.f, 0.f}, acc1 = {0.f, 0.f, 0.f, 0.f};
        bf16x8v a;
        a = *(const bf16x8v*)&a1_s[bm + d0];
        acc0 = __builtin_amdgcn_mfma_f32_16x16x32_bf16(a, bfrag[0][0], acc0, 0, 0, 0);
        acc1 = __builtin_amdgcn_mfma_f32_16x16x32_bf16(a, bfrag[0][1], acc1, 0, 0, 0);
        a = *(const bf16x8v*)&a1_s[bm + d1];
        acc0 = __builtin_amdgcn_mfma_f32_16x16x32_bf16(a, bfrag[1][0], acc0, 0, 0, 0);
        acc1 = __builtin_amdgcn_mfma_f32_16x16x32_bf16(a, bfrag[1][1], acc1, 0, 0, 0);
        a = *(const bf16x8v*)&a1_s[bm + d2];
        acc0 = __builtin_amdgcn_mfma_f32_16x16x32_bf16(a, bfrag[2][0], acc0, 0, 0, 0);
        acc1 = __builtin_amdgcn_mfma_f32_16x16x32_bf16(a, bfrag[2][1], acc1, 0, 0, 0);
        a = *(const bf16x8v*)&a1_s[bm + d3];
        acc0 = __builtin_amdgcn_mfma_f32_16x16x32_bf16(a, bfrag[3][0], acc0, 0, 0, 0);
        acc1 = __builtin_amdgcn_mfma_f32_16x16x32_bf16(a, bfrag[3][1], acc1, 0, 0, 0);
        a = *(const bf16x8v*)&a1_s[fqh ? (ab + A1_ZS) : (bm + 672 + icb)];
        acc0 = __builtin_amdgcn_mfma_f32_16x16x32_bf16(a, bfrag[4][0], acc0, 0, 0, 0);
        acc1 = __builtin_amdgcn_mfma_f32_16x16x32_bf16(a, bfrag[4][1], acc1, 0, 0, 0);

        bf16x8v ov;
#pragma unroll
        for (int j = 0; j < 4; ++j) {
            bool valid = (m * 16 + fq * 4 + j) < 110;
            float v0 = valid ? fminf(fmaxf(acc0[j], 0.f), 1.f) : 0.f;
            float v1 = valid ? fminf(fmaxf(acc1[j], 0.f), 1.f) : 0.f;
            ov[j]     = (__bf16)v0;
            ov[4 + j] = (__bf16)v1;
        }
        *(bf16x8v*)&a2p[(size_t)(t * 2048 + b) * FC3_K + m * 512 + lane * 8] = ov;
    }
}

// ---------------- fc3: one GEMM [20480 x 3584] * [3584 x 256] ----------
// 1-wave blocks: wave owns 64x64 tile (acc 4x4), NO barriers (LDS private),
// 2-buffer depth-2 prefetch sequenced purely by vmcnt(16). grid 1280 = 5
// blocks/CU balanced. XCD remap: 4 bn-sharers of a 64-row A panel on one XCD.
__global__ __launch_bounds__(64) void fc3_all_k(
    const __hip_bfloat16* __restrict__ A,   // [20480][3584]
    const __hip_bfloat16* __restrict__ W,   // [256][3584]
    __hip_bfloat16* __restrict__ a3)        // [20480][256]
{
    __shared__ __hip_bfloat16 As[2 * 64 * 64];   // 16 KiB
    __shared__ __hip_bfloat16 Bs[2 * 64 * 64];   // 16 KiB

    const int lane = threadIdx.x;

    const int d    = blockIdx.x;            // 0..1279
    const int xcd  = d & 7;
    const int slot = d >> 3;                // 0..159 within XCD
    const int n0   = (slot & 3) * 64;
    const int m0   = (xcd * 40 + (slot >> 2)) * 64;   // 64-row m-tiles, 0..319

    const int srow   = lane >> 3;
    const int schunk = lane & 7;
    const int swzc   = schunk ^ srow;

    const int fr = lane & 15;
    const int fq = lane >> 4;

    // 16 hoisted global sources (advanced +64 elements per STAGE)
    const __hip_bfloat16* gA0 = A + (size_t)(m0 +  0 + srow) * FC3_K + swzc * 8;
    const __hip_bfloat16* gA1 = A + (size_t)(m0 +  8 + srow) * FC3_K + swzc * 8;
    const __hip_bfloat16* gA2 = A + (size_t)(m0 + 16 + srow) * FC3_K + swzc * 8;
    const __hip_bfloat16* gA3 = A + (size_t)(m0 + 24 + srow) * FC3_K + swzc * 8;
    const __hip_bfloat16* gA4 = A + (size_t)(m0 + 32 + srow) * FC3_K + swzc * 8;
    const __hip_bfloat16* gA5 = A + (size_t)(m0 + 40 + srow) * FC3_K + swzc * 8;
    const __hip_bfloat16* gA6 = A + (size_t)(m0 + 48 + srow) * FC3_K + swzc * 8;
    const __hip_bfloat16* gA7 = A + (size_t)(m0 + 56 + srow) * FC3_K + swzc * 8;
    const __hip_bfloat16* gB0 = W + (size_t)(n0 +  0 + srow) * FC3_K + swzc * 8;
    const __hip_bfloat16* gB1 = W + (size_t)(n0 +  8 + srow) * FC3_K + swzc * 8;
    const __hip_bfloat16* gB2 = W + (size_t)(n0 + 16 + srow) * FC3_K + swzc * 8;
    const __hip_bfloat16* gB3 = W + (size_t)(n0 + 24 + srow) * FC3_K + swzc * 8;
    const __hip_bfloat16* gB4 = W + (size_t)(n0 + 32 + srow) * FC3_K + swzc * 8;
    const __hip_bfloat16* gB5 = W + (size_t)(n0 + 40 + srow) * FC3_K + swzc * 8;
    const __hip_bfloat16* gB6 = W + (size_t)(n0 + 48 + srow) * FC3_K + swzc * 8;
    const __hip_bfloat16* gB7 = W + (size_t)(n0 + 56 + srow) * FC3_K + swzc * 8;

#define GLD(src, dst, boff)                                                   \
    __builtin_amdgcn_global_load_lds(                                          \
        (const __attribute__((address_space(1))) void*)(src),                  \
        (__attribute__((address_space(3))) void*)((dst) + (boff)), 16, 0, 0)

// stage one K-tile into buffer b (elem offset b*4096 in As/Bs) and advance
#define STAGE(b)                                                               \
    do {                                                                       \
        GLD(gA0, As, (b) * 4096 +    0); GLD(gA1, As, (b) * 4096 +  512);      \
        GLD(gA2, As, (b) * 4096 + 1024); GLD(gA3, As, (b) * 4096 + 1536);      \
        GLD(gA4, As, (b) * 4096 + 2048); GLD(gA5, As, (b) * 4096 + 2560);      \
        GLD(gA6, As, (b) * 4096 + 3072); GLD(gA7, As, (b) * 4096 + 3584);      \
        GLD(gB0, Bs, (b) * 4096 +    0); GLD(gB1, Bs, (b) * 4096 +  512);      \
        GLD(gB2, Bs, (b) * 4096 + 1024); GLD(gB3, Bs, (b) * 4096 + 1536);      \
        GLD(gB4, Bs, (b) * 4096 + 2048); GLD(gB5, Bs, (b) * 4096 + 2560);      \
        GLD(gB6, Bs, (b) * 4096 + 3072); GLD(gB7, Bs, (b) * 4096 + 3584);      \
        gA0 += 64; gA1 += 64; gA2 += 64; gA3 += 64;                            \
        gA4 += 64; gA5 += 64; gA6 += 64; gA7 += 64;                            \
        gB0 += 64; gB1 += 64; gB2 += 64; gB3 += 64;                            \
        gB4 += 64; gB5 += 64; gB6 += 64; gB7 += 64;                            \
    } while (0)

    // precomputed ds_read element offsets (within one buffer)
    int tofs[2][4];
#pragma unroll
    for (int kk = 0; kk < 2; ++kk)
#pragma unroll
        for (int i = 0; i < 4; ++i) {
            const int rr = i * 16 + fr;
            tofs[kk][i] = rr * 64 + (((kk * 4 + fq) ^ (rr & 7)) * 8);
        }

    f32x4 acc[4][4];
#pragma unroll
    for (int mi = 0; mi < 4; ++mi)
#pragma unroll
        for (int ni = 0; ni < 4; ++ni)
            acc[mi][ni] = (f32x4){0.f, 0.f, 0.f, 0.f};

#define COMPUTE(b)                                                             \
    do {                                                                       \
        const __hip_bfloat16* Ab = &As[(b) * 4096];                            \
        const __hip_bfloat16* Bb = &Bs[(b) * 4096];                            \
        _Pragma("unroll")                                                      \
        for (int kk = 0; kk < 2; ++kk) {                                       \
            bf16x8v af[4], bfv[4];                                             \
            _Pragma("unroll")                                                  \
            for (int i = 0; i < 4; ++i) {                                      \
                af[i]  = *(const bf16x8v*)&Ab[tofs[kk][i]];                    \
                bfv[i] = *(const bf16x8v*)&Bb[tofs[kk][i]];                    \
            }                                                                  \
            __builtin_amdgcn_s_setprio(1);                                     \
            _Pragma("unroll")                                                  \
            for (int mi = 0; mi < 4; ++mi)                                     \
                _Pragma("unroll")                                              \
                for (int ni = 0; ni < 4; ++ni)                                 \
                    acc[mi][ni] = __builtin_amdgcn_mfma_f32_16x16x32_bf16(     \
                        af[mi], bfv[ni], acc[mi][ni], 0, 0, 0);                \
            __builtin_amdgcn_s_setprio(0);                                     \
        }                                                                      \
    } while (0)

    STAGE(0);                     // tile 0 -> buf0   (16 loads)
    STAGE(1);                     // tile 1 -> buf1   (32 loads in flight)

    // no barriers: LDS is wave-private. WAITV(16) = oldest tile landed;
    // restaging buf b after COMPUTE(b) is safe (reads consumed in-order
    // before the last MFMA; the "memory" clobber pins compiler order).
    for (int it = 0; it < 27; ++it) {
        WAITV(16); COMPUTE(0); STAGE(0);   // kt = 2it,   stage 2it+2
        WAITV(16); COMPUTE(1); STAGE(1);   // kt = 2it+1, stage 2it+3
    }
    WAITV(16); COMPUTE(0);        // kt 54
    WAITV(0);  COMPUTE(1);        // kt 55

#undef GLD
#undef STAGE
#undef COMPUTE

    // epilogue: clip -> bf16
#pragma unroll
    for (int mi = 0; mi < 4; ++mi)
#pragma unroll
        for (int ni = 0; ni < 4; ++ni)
#pragma unroll
            for (int j = 0; j < 4; ++j) {
                int row = m0 + mi * 16 + fq * 4 + j;
                int col = n0 + ni * 16 + fr;
                float v = fminf(fmaxf(acc[mi][ni][j], 0.f), 1.f);
                a3[(size_t)row * 256 + col] = __float2bfloat16(v);
            }
}

// ---------------- MGU all steps + fc5, one kernel (R8) ----------------
__global__ __launch_bounds__(256, 1) void mgu_all_k(
    const __hip_bfloat16* __restrict__ a3,  // [10*2048][256]
    const __hip_bfloat16* __restrict__ wfi, const __hip_bfloat16* __restrict__ wfh,
    const float* __restrict__ w5, float* __restrict__ out)
{
    __shared__ __hip_bfloat16 a3_s[16 * 256];
    __shared__ __hip_bfloat16 hq_s[16 * 64];
    __shared__ float hx_s[16 * 64];
    __shared__ float w5_s[7 * 64];

    const int tid = threadIdx.x;
    const int wv  = tid >> 6, lane = tid & 63;
    const int fr  = lane & 15, fq = lane >> 4;
    const int b0  = blockIdx.x * 16;
    const int ntf = wv, ntn = wv + 4;

    bf16x8v wiF[8][2], wiN[8][2], whF[2][2], whN[2][2];
#pragma unroll
    for (int kt = 0; kt < 8; ++kt)
#pragma unroll
        for (int hl = 0; hl < 2; ++hl) {
            wiF[kt][hl] = *(const bf16x8v*)&wfi[(((ntf * 8 + kt) * 2 + hl) * 64 + lane) * 8];
            wiN[kt][hl] = *(const bf16x8v*)&wfi[(((ntn * 8 + kt) * 2 + hl) * 64 + lane) * 8];
        }
#pragma unroll
    for (int kt = 0; kt < 2; ++kt)
#pragma unroll
        for (int hl = 0; hl < 2; ++hl) {
            whF[kt][hl] = *(const bf16x8v*)&wfh[(((ntf * 2 + kt) * 2 + hl) * 64 + lane) * 8];
            whN[kt][hl] = *(const bf16x8v*)&wfh[(((ntn * 2 + kt) * 2 + hl) * 64 + lane) * 8];
        }

    for (int i = tid; i < 16 * 64; i += 256) hx_s[i] = 0.f;
    for (int i = tid; i < 7 * 64; i += 256) w5_s[i] = w5[i];
    __syncthreads();

    for (int t = 0; t < 10; ++t) {
#pragma unroll
        for (int pass = 0; pass < 2; ++pass) {
            int i = pass * 256 + tid;
            int r = i >> 5, cq = i & 31;
            bf16x8v v = *(const bf16x8v*)&a3[((size_t)(t * 2048 + b0 + r)) * 256 + cq * 8];
            *(bf16x8v*)&a3_s[r * 256 + ((cq ^ (r & 7)) * 8)] = v;
        }
#pragma unroll
        for (int pass = 0; pass < 4; ++pass) {
            int i = pass * 256 + tid;
            int r = i >> 6, c = i & 63;
            float v = hx_s[r * 64 + c];
            v = fminf(fmaxf(v, -1.f), 1.f);
            v = rintf(v * 128.f) * 0.0078125f;
            hq_s[r * 64 + (((c >> 3) ^ (r & 7)) << 3) + (c & 7)] = __float2bfloat16(v);
        }
        __syncthreads();

        f32x4 accF  = {0.f, 0.f, 0.f, 0.f};
        f32x4 accNi = {0.f, 0.f, 0.f, 0.f};
        f32x4 accNh = {0.f, 0.f, 0.f, 0.f};
#pragma unroll
        for (int kt = 0; kt < 8; ++kt) {
            bf16x8v a = *(const bf16x8v*)&a3_s[fr * 256 + (((kt * 4 + fq) ^ (fr & 7)) * 8)];
            accF  = __builtin_amdgcn_mfma_f32_16x16x32_bf16(a, wiF[kt][0], accF, 0, 0, 0);
            accF  = __builtin_amdgcn_mfma_f32_16x16x32_bf16(a, wiF[kt][1], accF, 0, 0, 0);
            accNi = __builtin_amdgcn_mfma_f32_16x16x32_bf16(a, wiN[kt][0], accNi, 0, 0, 0);
            accNi = __builtin_amdgcn_mfma_f32_16x16x32_bf16(a, wiN[kt][1], accNi, 0, 0, 0);
        }
#pragma unroll
        for (int kt = 0; kt < 2; ++kt) {
            bf16x8v a = *(const bf16x8v*)&hq_s[fr * 64 + (((kt * 4 + fq) ^ (fr & 7)) * 8)];
            accF  = __builtin_amdgcn_mfma_f32_16x16x32_bf16(a, whF[kt][0], accF, 0, 0, 0);
            accF  = __builtin_amdgcn_mfma_f32_16x16x32_bf16(a, whF[kt][1], accF, 0, 0, 0);
            accNh = __builtin_amdgcn_mfma_f32_16x16x32_bf16(a, whN[kt][0], accNh, 0, 0, 0);
            accNh = __builtin_amdgcn_mfma_f32_16x16x32_bf16(a, whN[kt][1], accNh, 0, 0, 0);
        }

        const int j5 = wv * 16 + fr;
#pragma unroll
        for (int j = 0; j < 4; ++j) {
            int b = fq * 4 + j;
            float f = fminf(fmaxf(0.5f * accF[j] + 0.5f, 0.f), 1.f);
            float n = fminf(fmaxf(accNi[j] + f * accNh[j], -1.f), 1.f);
            float hq = __bfloat162float(
                hq_s[b * 64 + ((((j5) >> 3) ^ (b & 7)) << 3) + (j5 & 7)]);
            hx_s[b * 64 + j5] = (1.f - f) * n + f * hq;
        }
        __syncthreads();
    }

    if (tid < 112) {
        int b = tid / 7, c = tid % 7;
        float acc = 0.f;
#pragma unroll
        for (int k = 0; k < 64; ++k) acc += hx_s[b * 64 + k] * w5_s[c * 64 + k];
        out[(size_t)(b0 + b) * 7 + c] = acc;
    }
}

extern "C" void kernel_launch(void* const* d_in, const int* in_sizes, int n_in,
                              void* d_out, int out_size, void* d_ws, size_t ws_size,
                              hipStream_t stream)
{
    const float* x    = (const float*)d_in[0];
    const float* w1   = (const float*)d_in[1];
    const float* w2   = (const float*)d_in[2];
    const float* fc3w = (const float*)d_in[3];
    const float* wih  = (const float*)d_in[4];
    const float* whh  = (const float*)d_in[5];
    const float* fc5w = (const float*)d_in[6];
    float* out = (float*)d_out;

    char* ws = (char*)d_ws;
    __hip_bfloat16* a2p = (__hip_bfloat16*)ws;                     // 146,800,640
    __hip_bfloat16* a3  = (__hip_bfloat16*)(ws + 146800640);       //  10,485,760
    __hip_bfloat16* w3p = (__hip_bfloat16*)(ws + 157286400);       //   1,835,008
    __hip_bfloat16* w2p = (__hip_bfloat16*)(ws + 159121408);       //      10,240
    __hip_bfloat16* wfi = (__hip_bfloat16*)(ws + 159131648);       //     131,072
    __hip_bfloat16* wfh = (__hip_bfloat16*)(ws + 159262720);       //      32,768

    cvt_all_k<<<3924, 256, 0, stream>>>(fc3w, w2, wih, whh, w3p, w2p, wfi, wfh);
    conv_all_k<<<5120, 256, 0, stream>>>(x, w1, w2p, a2p);
    fc3_all_k<<<1280, 64, 0, stream>>>(a2p, w3p, a3);
    mgu_all_k<<<128, 256, 0, stream>>>(a3, wfi, wfh, fc5w, out);
}

// Round 13
// 116.664 us; speedup vs baseline: 1.7829x; 1.1602x over previous
//
#include <hip/hip_runtime.h>
#include <hip/hip_bf16.h>
#include <cstdint>
#include <cstddef>

// ---------------------------------------------------------------------------
// R13: R8 base (cvt_all, conv_all, mgu_all verbatim). fc3: same 128x64 tile +
//      2-barrier/K-step schedule as R8, but 2-wave blocks — each wave owns a
//      full 64x64 sub-tile (acc 4x4 -> 0.5 ds_reads per MFMA vs R8's 0.75).
//      48KB LDS -> 3 blocks/CU -> all 640 blocks co-resident (no tail).
// ---------------------------------------------------------------------------

typedef __bf16 bf16x8v __attribute__((ext_vector_type(8)));
typedef float  f32x4   __attribute__((ext_vector_type(4)));

#define WAVE_FENCE() asm volatile("s_waitcnt lgkmcnt(0)" ::: "memory")
#define WAITV(n) asm volatile("s_waitcnt vmcnt(" #n ")" ::: "memory")

#define A1_PS 24
#define A1_RS (13 * A1_PS)          // 312
#define A1_ZS (12 * A1_RS)          // zero slot
#define A1_BS 3776                  // per-batch elems (7552 B)
#define XQ_RS 20
#define XQ_BS 256

#define FC3_K 3584                  // permuted/padded K (7 Mtiles * 512)

// ---------------- all weight converts in one launch ----------------
__global__ __launch_bounds__(256) void cvt_all_k(
    const float* __restrict__ fc3w, const float* __restrict__ w2g,
    const float* __restrict__ wih,  const float* __restrict__ whh,
    __hip_bfloat16* __restrict__ w3p, __hip_bfloat16* __restrict__ w2p,
    __hip_bfloat16* __restrict__ wfi, __hip_bfloat16* __restrict__ wfh)
{
    int bid = blockIdx.x;
    if (bid < 3584) {
        int idx = bid * 256 + threadIdx.x;
        int n = idx / FC3_K, kp = idx % FC3_K;
        int mt = kp >> 9, r = kp & 511;
        int fq = r >> 7, col = (r >> 3) & 15, nt = (r >> 2) & 1, j = r & 3;
        int pixel = mt * 16 + fq * 4 + j, oc = nt * 16 + col;
        float v = (pixel < 110) ? fc3w[n * 3520 + oc * 110 + pixel] : 0.f;
        w3p[idx] = __float2bfloat16(v);
    } else if (bid < 3604) {
        int idx = (bid - 3584) * 256 + threadIdx.x;
        if (idx < 5120) {
            int oc = idx / 160, k = idx % 160;
            int koff = k >> 4, ic = k & 15;
            float v = (koff < 9) ? w2g[(oc * 16 + ic) * 9 + koff] : 0.f;
            w2p[idx] = __float2bfloat16(v);
        }
    } else if (bid < 3860) {
        int idx = (bid - 3604) * 256 + threadIdx.x;   // < 65536
        int e = idx & 7, lane = (idx >> 3) & 63, hl = (idx >> 9) & 1;
        int kt = (idx >> 10) & 7, nt = (idx >> 13) & 7;
        int gate = nt * 16 + (lane & 15);
        int k = kt * 32 + (lane >> 4) * 8 + e;
        float v = wih[gate * 256 + k];
        __hip_bfloat16 hi = __float2bfloat16(v);
        wfi[idx] = hl ? __float2bfloat16(v - __bfloat162float(hi)) : hi;
    } else {
        int idx = (bid - 3860) * 256 + threadIdx.x;   // < 16384
        int e = idx & 7, lane = (idx >> 3) & 63, hl = (idx >> 9) & 1;
        int kt = (idx >> 10) & 1, nt = (idx >> 11) & 7;
        int gate = nt * 16 + (lane & 15);
        int k = kt * 32 + (lane >> 4) * 8 + e;
        float v = whh[gate * 64 + k];
        __hip_bfloat16 hi = __float2bfloat16(v);
        wfh[idx] = hl ? __float2bfloat16(v - __bfloat162float(hi)) : hi;
    }
}

// ---------------- all-steps fused quant + conv1 + conv2 (R8) ----------------
__global__ __launch_bounds__(256) void conv_all_k(
    const float* __restrict__ x, const float* __restrict__ w1g,
    const __hip_bfloat16* __restrict__ w2p,
    __hip_bfloat16* __restrict__ a2p)
{
    __shared__ __hip_bfloat16 a1_s[4 * A1_BS];
    __shared__ float xq_s[4 * XQ_BS];

    const int tid  = threadIdx.x;
    const int wv   = tid >> 6, lane = tid & 63;
    const int t    = blockIdx.x >> 9;
    const int b    = (blockIdx.x & 511) * 4 + wv;
    const int ab   = wv * A1_BS;
    const int xb   = wv * XQ_BS;

    const int fr  = lane & 15, fq = lane >> 4;
    const int fqh = fq >> 1,  icb = (fq & 1) * 8;

    bf16x8v bfrag[5][2];
#pragma unroll
    for (int kt = 0; kt < 5; ++kt)
#pragma unroll
        for (int nt = 0; nt < 2; ++nt)
            bfrag[kt][nt] = *(const bf16x8v*)&w2p[(nt * 16 + fr) * 160 + kt * 32 + fq * 8];

    const int ocp = lane & 7, rs = lane >> 3;
    float w1a[9], w1b[9];
#pragma unroll
    for (int k = 0; k < 9; ++k) {
        w1a[k] = w1g[(2 * ocp) * 9 + k];
        w1b[k] = w1g[(2 * ocp + 1) * 9 + k];
    }

    {
        bf16x8v z = {};
#pragma unroll
        for (int i = 0; i < 8; ++i) {
            int c = lane + i * 64;
            if (c < A1_BS / 8) *(bf16x8v*)&a1_s[ab + c * 8] = z;
        }
        float4 zf = {0.f, 0.f, 0.f, 0.f};
        *(float4*)&xq_s[xb + lane * 4] = zf;
    }
    WAVE_FENCE();

#pragma unroll
    for (int pass = 0; pass < 2; ++pass) {
        int p = pass * 64 + lane;
        if (p < 110) {
            float xv = x[(size_t)b * 1100 + t * 110 + p];
            xv = fminf(fmaxf(xv, -1.f), 1.f);
            xv = rintf(xv * 128.f) * 0.0078125f;
            int h = p / 11, w = p - h * 11;
            xq_s[xb + (h + 1) * XQ_RS + (w + 1)] = xv;
        }
    }
    WAVE_FENCE();

#pragma unroll
    for (int pass = 0; pass < 2; ++pass) {
        const int hr = pass == 0 ? rs : rs + 8;
        if (hr < 10) {
            float acc0[11], acc1[11];
#pragma unroll
            for (int w = 0; w < 11; ++w) { acc0[w] = 0.f; acc1[w] = 0.f; }
#pragma unroll
            for (int dr = 0; dr < 3; ++dr) {
                float xr[16];
                const float* row = &xq_s[xb + (hr + dr) * XQ_RS];
#pragma unroll
                for (int j = 0; j < 4; ++j)
                    *(float4*)&xr[j * 4] = *(const float4*)&row[j * 4];
#pragma unroll
                for (int dc = 0; dc < 3; ++dc) {
                    float wa = w1a[dr * 3 + dc], wb = w1b[dr * 3 + dc];
#pragma unroll
                    for (int w = 0; w < 11; ++w) {
                        acc0[w] += xr[w + dc] * wa;
                        acc1[w] += xr[w + dc] * wb;
                    }
                }
            }
#pragma unroll
            for (int w = 0; w < 11; ++w) {
                __hip_bfloat162 pr;
                pr.x = __float2bfloat16(fminf(fmaxf(acc0[w], 0.f), 1.f));
                pr.y = __float2bfloat16(fminf(fmaxf(acc1[w], 0.f), 1.f));
                *(__hip_bfloat162*)&a1_s[ab + (hr + 1) * A1_RS + (w + 1) * A1_PS + 2 * ocp] = pr;
            }
        }
    }
    WAVE_FENCE();

    const int d0 = fqh * 24 + icb;
    const int d1 = (fqh ? 312 : 48) + icb;
    const int d2 = 336 + fqh * 24 + icb;
    const int d3 = 624 + fqh * 24 + icb;

#pragma unroll
    for (int m = 0; m < 7; ++m) {
        int p = m * 16 + fr; if (p > 109) p = 109;
        int h = p / 11, w = p - h * 11;
        const int bm = ab + h * A1_RS + w * A1_PS;
        f32x4 acc0 = {0.f, 0.f, 0.f, 0.f}, acc1 = {0.f, 0.f, 0.f, 0.f};
        bf16x8v a;
        a = *(const bf16x8v*)&a1_s[bm + d0];
        acc0 = __builtin_amdgcn_mfma_f32_16x16x32_bf16(a, bfrag[0][0], acc0, 0, 0, 0);
        acc1 = __builtin_amdgcn_mfma_f32_16x16x32_bf16(a, bfrag[0][1], acc1, 0, 0, 0);
        a = *(const bf16x8v*)&a1_s[bm + d1];
        acc0 = __builtin_amdgcn_mfma_f32_16x16x32_bf16(a, bfrag[1][0], acc0, 0, 0, 0);
        acc1 = __builtin_amdgcn_mfma_f32_16x16x32_bf16(a, bfrag[1][1], acc1, 0, 0, 0);
        a = *(const bf16x8v*)&a1_s[bm + d2];
        acc0 = __builtin_amdgcn_mfma_f32_16x16x32_bf16(a, bfrag[2][0], acc0, 0, 0, 0);
        acc1 = __builtin_amdgcn_mfma_f32_16x16x32_bf16(a, bfrag[2][1], acc1, 0, 0, 0);
        a = *(const bf16x8v*)&a1_s[bm + d3];
        acc0 = __builtin_amdgcn_mfma_f32_16x16x32_bf16(a, bfrag[3][0], acc0, 0, 0, 0);
        acc1 = __builtin_amdgcn_mfma_f32_16x16x32_bf16(a, bfrag[3][1], acc1, 0, 0, 0);
        a = *(const bf16x8v*)&a1_s[fqh ? (ab + A1_ZS) : (bm + 672 + icb)];
        acc0 = __builtin_amdgcn_mfma_f32_16x16x32_bf16(a, bfrag[4][0], acc0, 0, 0, 0);
        acc1 = __builtin_amdgcn_mfma_f32_16x16x32_bf16(a, bfrag[4][1], acc1, 0, 0, 0);

        bf16x8v ov;
#pragma unroll
        for (int j = 0; j < 4; ++j) {
            bool valid = (m * 16 + fq * 4 + j) < 110;
            float v0 = valid ? fminf(fmaxf(acc0[j], 0.f), 1.f) : 0.f;
            float v1 = valid ? fminf(fmaxf(acc1[j], 0.f), 1.f) : 0.f;
            ov[j]     = (__bf16)v0;
            ov[4 + j] = (__bf16)v1;
        }
        *(bf16x8v*)&a2p[(size_t)(t * 2048 + b) * FC3_K + m * 512 + lane * 8] = ov;
    }
}

// ---------------- fc3: one GEMM [20480 x 3584] * [3584 x 256] ----------
// 128x64 tile, 2 waves: wave wv owns rows [wv*64, wv*64+64) x all 64 cols,
// acc 4x4 (0.5 ds_read per MFMA). R8 2-barrier/K-step schedule, depth-2
// prefetch (24 loads in flight/wave-pair, WAITV(12)/wave). 48KB LDS -> all
// 640 blocks co-resident. XCD remap as R8.
__global__ __launch_bounds__(128) void fc3_all_k(
    const __hip_bfloat16* __restrict__ A,   // [20480][3584]
    const __hip_bfloat16* __restrict__ W,   // [256][3584]
    __hip_bfloat16* __restrict__ a3)        // [20480][256]
{
    __shared__ __hip_bfloat16 As[2 * 128 * 64];  // 32 KiB
    __shared__ __hip_bfloat16 Bs[2 * 64 * 64];   // 16 KiB

    const int tid  = threadIdx.x;
    const int wv   = tid >> 6;              // 0/1
    const int lane = tid & 63;

    const int d    = blockIdx.x;            // 0..639
    const int xcd  = d & 7;
    const int slot = d >> 3;                // 0..79 within XCD
    const int n0   = (slot & 3) * 64;
    const int m0   = (xcd * 20 + (slot >> 2)) * 128;

    const int srow   = lane >> 3;
    const int schunk = lane & 7;
    const int swzc   = schunk ^ srow;

    const int fr = lane & 15;
    const int fq = lane >> 4;

    // per-wave staging: A rows [wv*64, +64) (8 gloads), B rows [wv*32, +32) (4)
    const __hip_bfloat16* gA0 = A + (size_t)(m0 + wv * 64 +  0 + srow) * FC3_K + swzc * 8;
    const __hip_bfloat16* gA1 = A + (size_t)(m0 + wv * 64 +  8 + srow) * FC3_K + swzc * 8;
    const __hip_bfloat16* gA2 = A + (size_t)(m0 + wv * 64 + 16 + srow) * FC3_K + swzc * 8;
    const __hip_bfloat16* gA3 = A + (size_t)(m0 + wv * 64 + 24 + srow) * FC3_K + swzc * 8;
    const __hip_bfloat16* gA4 = A + (size_t)(m0 + wv * 64 + 32 + srow) * FC3_K + swzc * 8;
    const __hip_bfloat16* gA5 = A + (size_t)(m0 + wv * 64 + 40 + srow) * FC3_K + swzc * 8;
    const __hip_bfloat16* gA6 = A + (size_t)(m0 + wv * 64 + 48 + srow) * FC3_K + swzc * 8;
    const __hip_bfloat16* gA7 = A + (size_t)(m0 + wv * 64 + 56 + srow) * FC3_K + swzc * 8;
    const __hip_bfloat16* gB0 = W + (size_t)(n0 + wv * 32 +  0 + srow) * FC3_K + swzc * 8;
    const __hip_bfloat16* gB1 = W + (size_t)(n0 + wv * 32 +  8 + srow) * FC3_K + swzc * 8;
    const __hip_bfloat16* gB2 = W + (size_t)(n0 + wv * 32 + 16 + srow) * FC3_K + swzc * 8;
    const __hip_bfloat16* gB3 = W + (size_t)(n0 + wv * 32 + 24 + srow) * FC3_K + swzc * 8;

    __hip_bfloat16* ldsA0 = &As[(wv * 64 +  0) * 64];
    __hip_bfloat16* ldsA1 = &As[(wv * 64 +  8) * 64];
    __hip_bfloat16* ldsA2 = &As[(wv * 64 + 16) * 64];
    __hip_bfloat16* ldsA3 = &As[(wv * 64 + 24) * 64];
    __hip_bfloat16* ldsA4 = &As[(wv * 64 + 32) * 64];
    __hip_bfloat16* ldsA5 = &As[(wv * 64 + 40) * 64];
    __hip_bfloat16* ldsA6 = &As[(wv * 64 + 48) * 64];
    __hip_bfloat16* ldsA7 = &As[(wv * 64 + 56) * 64];
    __hip_bfloat16* ldsB0 = &Bs[(wv * 32 +  0) * 64];
    __hip_bfloat16* ldsB1 = &Bs[(wv * 32 +  8) * 64];
    __hip_bfloat16* ldsB2 = &Bs[(wv * 32 + 16) * 64];
    __hip_bfloat16* ldsB3 = &Bs[(wv * 32 + 24) * 64];

#define GLD(src, dst, boff)                                                   \
    __builtin_amdgcn_global_load_lds(                                          \
        (const __attribute__((address_space(1))) void*)(src),                  \
        (__attribute__((address_space(3))) void*)((dst) + (boff)), 16, 0, 0)

// stage one K-tile into buffer b (A +b*8192, B +b*4096 elems) and advance
#define STAGE(b)                                                               \
    do {                                                                       \
        GLD(gA0, ldsA0, (b) * 8192); GLD(gA1, ldsA1, (b) * 8192);              \
        GLD(gA2, ldsA2, (b) * 8192); GLD(gA3, ldsA3, (b) * 8192);              \
        GLD(gA4, ldsA4, (b) * 8192); GLD(gA5, ldsA5, (b) * 8192);              \
        GLD(gA6, ldsA6, (b) * 8192); GLD(gA7, ldsA7, (b) * 8192);              \
        GLD(gB0, ldsB0, (b) * 4096); GLD(gB1, ldsB1, (b) * 4096);              \
        GLD(gB2, ldsB2, (b) * 4096); GLD(gB3, ldsB3, (b) * 4096);              \
        gA0 += 64; gA1 += 64; gA2 += 64; gA3 += 64;                            \
        gA4 += 64; gA5 += 64; gA6 += 64; gA7 += 64;                            \
        gB0 += 64; gB1 += 64; gB2 += 64; gB3 += 64;                            \
    } while (0)

    // precomputed ds_read element offsets (within one buffer)
    int aofs[2][4], bofs[2][4];
#pragma unroll
    for (int kk = 0; kk < 2; ++kk) {
#pragma unroll
        for (int mi = 0; mi < 4; ++mi) {
            const int rr = wv * 64 + mi * 16 + fr;
            aofs[kk][mi] = rr * 64 + (((kk * 4 + fq) ^ (rr & 7)) * 8);
        }
#pragma unroll
        for (int ni = 0; ni < 4; ++ni) {
            const int rr = ni * 16 + fr;
            bofs[kk][ni] = rr * 64 + (((kk * 4 + fq) ^ (rr & 7)) * 8);
        }
    }

    f32x4 acc[4][4];
#pragma unroll
    for (int mi = 0; mi < 4; ++mi)
#pragma unroll
        for (int ni = 0; ni < 4; ++ni)
            acc[mi][ni] = (f32x4){0.f, 0.f, 0.f, 0.f};

#define COMPUTE(b)                                                             \
    do {                                                                       \
        const __hip_bfloat16* Ab = &As[(b) * 8192];                            \
        const __hip_bfloat16* Bb = &Bs[(b) * 4096];                            \
        _Pragma("unroll")                                                      \
        for (int kk = 0; kk < 2; ++kk) {                                       \
            bf16x8v af[4], bfv[4];                                             \
            _Pragma("unroll")                                                  \
            for (int i = 0; i < 4; ++i) {                                      \
                af[i]  = *(const bf16x8v*)&Ab[aofs[kk][i]];                    \
                bfv[i] = *(const bf16x8v*)&Bb[bofs[kk][i]];                    \
            }                                                                  \
            _Pragma("unroll")                                                  \
            for (int mi = 0; mi < 4; ++mi)                                     \
                _Pragma("unroll")                                              \
                for (int ni = 0; ni < 4; ++ni)                                 \
                    acc[mi][ni] = __builtin_amdgcn_mfma_f32_16x16x32_bf16(     \
                        af[mi], bfv[ni], acc[mi][ni], 0, 0, 0);                \
        }                                                                      \
    } while (0)

    STAGE(0);                     // kt 0 -> buf0   (12 loads/wave)
    STAGE(1);                     // kt 1 -> buf1   (24 in flight/wave)

    for (int it = 0; it < 27; ++it) {
        WAITV(12);
        __builtin_amdgcn_s_barrier();
        COMPUTE(0);
        __builtin_amdgcn_s_barrier();
        STAGE(0);
        WAITV(12);
        __builtin_amdgcn_s_barrier();
        COMPUTE(1);
        __builtin_amdgcn_s_barrier();
        STAGE(1);
    }
    WAITV(12);
    __builtin_amdgcn_s_barrier();
    COMPUTE(0);
    WAITV(0);
    __builtin_amdgcn_s_barrier();
    COMPUTE(1);

#undef GLD
#undef STAGE
#undef COMPUTE

    // epilogue: clip -> bf16
#pragma unroll
    for (int mi = 0; mi < 4; ++mi)
#pragma unroll
        for (int ni = 0; ni < 4; ++ni)
#pragma unroll
            for (int j = 0; j < 4; ++j) {
                int row = m0 + wv * 64 + mi * 16 + fq * 4 + j;
                int col = n0 + ni * 16 + fr;
                float v = fminf(fmaxf(acc[mi][ni][j], 0.f), 1.f);
                a3[(size_t)row * 256 + col] = __float2bfloat16(v);
            }
}

// ---------------- MGU all steps + fc5, one kernel (R8) ----------------
__global__ __launch_bounds__(256, 1) void mgu_all_k(
    const __hip_bfloat16* __restrict__ a3,  // [10*2048][256]
    const __hip_bfloat16* __restrict__ wfi, const __hip_bfloat16* __restrict__ wfh,
    const float* __restrict__ w5, float* __restrict__ out)
{
    __shared__ __hip_bfloat16 a3_s[16 * 256];
    __shared__ __hip_bfloat16 hq_s[16 * 64];
    __shared__ float hx_s[16 * 64];
    __shared__ float w5_s[7 * 64];

    const int tid = threadIdx.x;
    const int wv  = tid >> 6, lane = tid & 63;
    const int fr  = lane & 15, fq = lane >> 4;
    const int b0  = blockIdx.x * 16;
    const int ntf = wv, ntn = wv + 4;

    bf16x8v wiF[8][2], wiN[8][2], whF[2][2], whN[2][2];
#pragma unroll
    for (int kt = 0; kt < 8; ++kt)
#pragma unroll
        for (int hl = 0; hl < 2; ++hl) {
            wiF[kt][hl] = *(const bf16x8v*)&wfi[(((ntf * 8 + kt) * 2 + hl) * 64 + lane) * 8];
            wiN[kt][hl] = *(const bf16x8v*)&wfi[(((ntn * 8 + kt) * 2 + hl) * 64 + lane) * 8];
        }
#pragma unroll
    for (int kt = 0; kt < 2; ++kt)
#pragma unroll
        for (int hl = 0; hl < 2; ++hl) {
            whF[kt][hl] = *(const bf16x8v*)&wfh[(((ntf * 2 + kt) * 2 + hl) * 64 + lane) * 8];
            whN[kt][hl] = *(const bf16x8v*)&wfh[(((ntn * 2 + kt) * 2 + hl) * 64 + lane) * 8];
        }

    for (int i = tid; i < 16 * 64; i += 256) hx_s[i] = 0.f;
    for (int i = tid; i < 7 * 64; i += 256) w5_s[i] = w5[i];
    __syncthreads();

    for (int t = 0; t < 10; ++t) {
#pragma unroll
        for (int pass = 0; pass < 2; ++pass) {
            int i = pass * 256 + tid;
            int r = i >> 5, cq = i & 31;
            bf16x8v v = *(const bf16x8v*)&a3[((size_t)(t * 2048 + b0 + r)) * 256 + cq * 8];
            *(bf16x8v*)&a3_s[r * 256 + ((cq ^ (r & 7)) * 8)] = v;
        }
#pragma unroll
        for (int pass = 0; pass < 4; ++pass) {
            int i = pass * 256 + tid;
            int r = i >> 6, c = i & 63;
            float v = hx_s[r * 64 + c];
            v = fminf(fmaxf(v, -1.f), 1.f);
            v = rintf(v * 128.f) * 0.0078125f;
            hq_s[r * 64 + (((c >> 3) ^ (r & 7)) << 3) + (c & 7)] = __float2bfloat16(v);
        }
        __syncthreads();

        f32x4 accF  = {0.f, 0.f, 0.f, 0.f};
        f32x4 accNi = {0.f, 0.f, 0.f, 0.f};
        f32x4 accNh = {0.f, 0.f, 0.f, 0.f};
#pragma unroll
        for (int kt = 0; kt < 8; ++kt) {
            bf16x8v a = *(const bf16x8v*)&a3_s[fr * 256 + (((kt * 4 + fq) ^ (fr & 7)) * 8)];
            accF  = __builtin_amdgcn_mfma_f32_16x16x32_bf16(a, wiF[kt][0], accF, 0, 0, 0);
            accF  = __builtin_amdgcn_mfma_f32_16x16x32_bf16(a, wiF[kt][1], accF, 0, 0, 0);
            accNi = __builtin_amdgcn_mfma_f32_16x16x32_bf16(a, wiN[kt][0], accNi, 0, 0, 0);
            accNi = __builtin_amdgcn_mfma_f32_16x16x32_bf16(a, wiN[kt][1], accNi, 0, 0, 0);
        }
#pragma unroll
        for (int kt = 0; kt < 2; ++kt) {
            bf16x8v a = *(const bf16x8v*)&hq_s[fr * 64 + (((kt * 4 + fq) ^ (fr & 7)) * 8)];
            accF  = __builtin_amdgcn_mfma_f32_16x16x32_bf16(a, whF[kt][0], accF, 0, 0, 0);
            accF  = __builtin_amdgcn_mfma_f32_16x16x32_bf16(a, whF[kt][1], accF, 0, 0, 0);
            accNh = __builtin_amdgcn_mfma_f32_16x16x32_bf16(a, whN[kt][0], accNh, 0, 0, 0);
            accNh = __builtin_amdgcn_mfma_f32_16x16x32_bf16(a, whN[kt][1], accNh, 0, 0, 0);
        }

        const int j5 = wv * 16 + fr;
#pragma unroll
        for (int j = 0; j < 4; ++j) {
            int b = fq * 4 + j;
            float f = fminf(fmaxf(0.5f * accF[j] + 0.5f, 0.f), 1.f);
            float n = fminf(fmaxf(accNi[j] + f * accNh[j], -1.f), 1.f);
            float hq = __bfloat162float(
                hq_s[b * 64 + ((((j5) >> 3) ^ (b & 7)) << 3) + (j5 & 7)]);
            hx_s[b * 64 + j5] = (1.f - f) * n + f * hq;
        }
        __syncthreads();
    }

    if (tid < 112) {
        int b = tid / 7, c = tid % 7;
        float acc = 0.f;
#pragma unroll
        for (int k = 0; k < 64; ++k) acc += hx_s[b * 64 + k] * w5_s[c * 64 + k];
        out[(size_t)(b0 + b) * 7 + c] = acc;
    }
}

extern "C" void kernel_launch(void* const* d_in, const int* in_sizes, int n_in,
                              void* d_out, int out_size, void* d_ws, size_t ws_size,
                              hipStream_t stream)
{
    const float* x    = (const float*)d_in[0];
    const float* w1   = (const float*)d_in[1];
    const float* w2   = (const float*)d_in[2];
    const float* fc3w = (const float*)d_in[3];
    const float* wih  = (const float*)d_in[4];
    const float* whh  = (const float*)d_in[5];
    const float* fc5w = (const float*)d_in[6];
    float* out = (float*)d_out;

    char* ws = (char*)d_ws;
    __hip_bfloat16* a2p = (__hip_bfloat16*)ws;                     // 146,800,640
    __hip_bfloat16* a3  = (__hip_bfloat16*)(ws + 146800640);       //  10,485,760
    __hip_bfloat16* w3p = (__hip_bfloat16*)(ws + 157286400);       //   1,835,008
    __hip_bfloat16* w2p = (__hip_bfloat16*)(ws + 159121408);       //      10,240
    __hip_bfloat16* wfi = (__hip_bfloat16*)(ws + 159131648);       //     131,072
    __hip_bfloat16* wfh = (__hip_bfloat16*)(ws + 159262720);       //      32,768

    cvt_all_k<<<3924, 256, 0, stream>>>(fc3w, w2, wih, whh, w3p, w2p, wfi, wfh);
    conv_all_k<<<5120, 256, 0, stream>>>(x, w1, w2p, a2p);
    fc3_all_k<<<640, 128, 0, stream>>>(a2p, w3p, a3);
    mgu_all_k<<<128, 256, 0, stream>>>(a3, wfi, wfh, fc5w, out);
}

// Round 14
// 113.751 us; speedup vs baseline: 1.8285x; 1.0256x over previous
//
#include <hip/hip_runtime.h>
#include <hip/hip_bf16.h>
#include <cstdint>
#include <cstddef>

// ---------------------------------------------------------------------------
// R14: R8 config (best known: 111.2us) + low-risk wins:
//      - conv: halo-only a1 zeroing (140 chunks vs 472), pk-fma conv1
//      - cvt: 981 blocks (4 virtual blocks each)
//      fc3 (4-wave 128x64 2-buffer vmcnt(6)) and mgu verbatim from R8.
//      fc3 variants R9/R12/R13 all lost on occupancy — R8 is the optimum.
// ---------------------------------------------------------------------------

typedef __bf16 bf16x8v __attribute__((ext_vector_type(8)));
typedef float  f32x4   __attribute__((ext_vector_type(4)));
typedef float  f32x2   __attribute__((ext_vector_type(2)));

#define WAVE_FENCE() asm volatile("s_waitcnt lgkmcnt(0)" ::: "memory")
#define WAITV(n) asm volatile("s_waitcnt vmcnt(" #n ")" ::: "memory")

#define A1_PS 24
#define A1_RS (13 * A1_PS)          // 312 elems/row (39 b128 chunks)
#define A1_ZS (12 * A1_RS)          // 3744: zero slot
#define A1_BS 3776                  // per-batch elems (7552 B)
#define XQ_RS 20
#define XQ_BS 256

#define FC3_K 3584                  // permuted/padded K (7 Mtiles * 512)

// ---------------- all weight converts, 4 virtual blocks per block ----------
__global__ __launch_bounds__(256) void cvt_all_k(
    const float* __restrict__ fc3w, const float* __restrict__ w2g,
    const float* __restrict__ wih,  const float* __restrict__ whh,
    __hip_bfloat16* __restrict__ w3p, __hip_bfloat16* __restrict__ w2p,
    __hip_bfloat16* __restrict__ wfi, __hip_bfloat16* __restrict__ wfh)
{
#pragma unroll
    for (int s = 0; s < 4; ++s) {
        int bid = blockIdx.x * 4 + s;
        if (bid >= 3924) break;
        if (bid < 3584) {
            int idx = bid * 256 + threadIdx.x;
            int n = idx / FC3_K, kp = idx % FC3_K;
            int mt = kp >> 9, r = kp & 511;
            int fq = r >> 7, col = (r >> 3) & 15, nt = (r >> 2) & 1, j = r & 3;
            int pixel = mt * 16 + fq * 4 + j, oc = nt * 16 + col;
            float v = (pixel < 110) ? fc3w[n * 3520 + oc * 110 + pixel] : 0.f;
            w3p[idx] = __float2bfloat16(v);
        } else if (bid < 3604) {
            int idx = (bid - 3584) * 256 + threadIdx.x;
            if (idx < 5120) {
                int oc = idx / 160, k = idx % 160;
                int koff = k >> 4, ic = k & 15;
                float v = (koff < 9) ? w2g[(oc * 16 + ic) * 9 + koff] : 0.f;
                w2p[idx] = __float2bfloat16(v);
            }
        } else if (bid < 3860) {
            int idx = (bid - 3604) * 256 + threadIdx.x;   // < 65536
            int e = idx & 7, lane = (idx >> 3) & 63, hl = (idx >> 9) & 1;
            int kt = (idx >> 10) & 7, nt = (idx >> 13) & 7;
            int gate = nt * 16 + (lane & 15);
            int k = kt * 32 + (lane >> 4) * 8 + e;
            float v = wih[gate * 256 + k];
            __hip_bfloat16 hi = __float2bfloat16(v);
            wfi[idx] = hl ? __float2bfloat16(v - __bfloat162float(hi)) : hi;
        } else {
            int idx = (bid - 3860) * 256 + threadIdx.x;   // < 16384
            int e = idx & 7, lane = (idx >> 3) & 63, hl = (idx >> 9) & 1;
            int kt = (idx >> 10) & 1, nt = (idx >> 11) & 7;
            int gate = nt * 16 + (lane & 15);
            int k = kt * 32 + (lane >> 4) * 8 + e;
            float v = whh[gate * 64 + k];
            __hip_bfloat16 hi = __float2bfloat16(v);
            wfh[idx] = hl ? __float2bfloat16(v - __bfloat162float(hi)) : hi;
        }
    }
}

// ---------------- all-steps fused quant + conv1 + conv2 ----------------
// grid 5120 = 10 t * 512; block = 4 waves, wave = 1 (batch, t), no barriers.
__global__ __launch_bounds__(256) void conv_all_k(
    const float* __restrict__ x, const float* __restrict__ w1g,
    const __hip_bfloat16* __restrict__ w2p,
    __hip_bfloat16* __restrict__ a2p)
{
    __shared__ __hip_bfloat16 a1_s[4 * A1_BS];
    __shared__ float xq_s[4 * XQ_BS];

    const int tid  = threadIdx.x;
    const int wv   = tid >> 6, lane = tid & 63;
    const int t    = blockIdx.x >> 9;
    const int b    = (blockIdx.x & 511) * 4 + wv;
    const int ab   = wv * A1_BS;
    const int xb   = wv * XQ_BS;

    const int fr  = lane & 15, fq = lane >> 4;
    const int fqh = fq >> 1,  icb = (fq & 1) * 8;

    bf16x8v bfrag[5][2];
#pragma unroll
    for (int kt = 0; kt < 5; ++kt)
#pragma unroll
        for (int nt = 0; nt < 2; ++nt)
            bfrag[kt][nt] = *(const bf16x8v*)&w2p[(nt * 16 + fr) * 160 + kt * 32 + fq * 8];

    const int ocp = lane & 7, rs = lane >> 3;
    f32x2 w1v[9];
#pragma unroll
    for (int k = 0; k < 9; ++k) {
        w1v[k][0] = w1g[(2 * ocp) * 9 + k];
        w1v[k][1] = w1g[(2 * ocp + 1) * 9 + k];
    }

    // halo-only zeroing: 140 b128 chunks = row0 (39), row11 (39),
    // col0 rows1..10 (30), col12 rows1..10 (30), zero-slot (2).
    // Interior slots are fully written by conv1; slot pads (elems 16..23)
    // are never read (all conv2 read offsets land at slot elem 0 or 8).
    {
        bf16x8v z = {};
#pragma unroll
        for (int i = lane; i < 140; i += 64) {
            int ch;
            if (i < 39)       ch = i;                                    // row 0
            else if (i < 78)  ch = 429 + (i - 39);                       // row 11
            else if (i < 108) { int r = (i - 78) / 3 + 1;  ch = r * 39 + (i - 78) % 3; }        // col 0
            else if (i < 138) { int r = (i - 108) / 3 + 1; ch = r * 39 + 36 + (i - 108) % 3; }  // col 12
            else              ch = 468 + (i - 138);                      // zero slot
            *(bf16x8v*)&a1_s[ab + ch * 8] = z;
        }
        float4 zf = {0.f, 0.f, 0.f, 0.f};
        *(float4*)&xq_s[xb + lane * 4] = zf;
    }
    WAVE_FENCE();

#pragma unroll
    for (int pass = 0; pass < 2; ++pass) {
        int p = pass * 64 + lane;
        if (p < 110) {
            float xv = x[(size_t)b * 1100 + t * 110 + p];
            xv = fminf(fmaxf(xv, -1.f), 1.f);
            xv = rintf(xv * 128.f) * 0.0078125f;
            int h = p / 11, w = p - h * 11;
            xq_s[xb + (h + 1) * XQ_RS + (w + 1)] = xv;
        }
    }
    WAVE_FENCE();

    // conv1: lane does oc pair (2*ocp,2*ocp+1) for image row(s) rs (+8),
    // f32x2 accumulators -> v_pk_fma_f32 (bit-identical IEEE fma)
#pragma unroll
    for (int pass = 0; pass < 2; ++pass) {
        const int hr = pass == 0 ? rs : rs + 8;
        if (hr < 10) {
            f32x2 acc[11];
#pragma unroll
            for (int w = 0; w < 11; ++w) acc[w] = (f32x2){0.f, 0.f};
#pragma unroll
            for (int dr = 0; dr < 3; ++dr) {
                float xr[16];
                const float* row = &xq_s[xb + (hr + dr) * XQ_RS];
#pragma unroll
                for (int j = 0; j < 4; ++j)
                    *(float4*)&xr[j * 4] = *(const float4*)&row[j * 4];
#pragma unroll
                for (int dc = 0; dc < 3; ++dc) {
                    f32x2 wv2 = w1v[dr * 3 + dc];
#pragma unroll
                    for (int w = 0; w < 11; ++w)
                        acc[w] += wv2 * xr[w + dc];
                }
            }
#pragma unroll
            for (int w = 0; w < 11; ++w) {
                __hip_bfloat162 pr;
                pr.x = __float2bfloat16(fminf(fmaxf(acc[w][0], 0.f), 1.f));
                pr.y = __float2bfloat16(fminf(fmaxf(acc[w][1], 0.f), 1.f));
                *(__hip_bfloat162*)&a1_s[ab + (hr + 1) * A1_RS + (w + 1) * A1_PS + 2 * ocp] = pr;
            }
        }
    }
    WAVE_FENCE();

    const int d0 = fqh * 24 + icb;
    const int d1 = (fqh ? 312 : 48) + icb;
    const int d2 = 336 + fqh * 24 + icb;
    const int d3 = 624 + fqh * 24 + icb;

#pragma unroll
    for (int m = 0; m < 7; ++m) {
        int p = m * 16 + fr; if (p > 109) p = 109;
        int h = p / 11, w = p - h * 11;
        const int bm = ab + h * A1_RS + w * A1_PS;
        f32x4 acc0 = {0.f, 0.f, 0.f, 0.f}, acc1 = {0.f, 0.f, 0.f, 0.f};
        bf16x8v a;
        a = *(const bf16x8v*)&a1_s[bm + d0];
        acc0 = __builtin_amdgcn_mfma_f32_16x16x32_bf16(a, bfrag[0][0], acc0, 0, 0, 0);
        acc1 = __builtin_amdgcn_mfma_f32_16x16x32_bf16(a, bfrag[0][1], acc1, 0, 0, 0);
        a = *(const bf16x8v*)&a1_s[bm + d1];
        acc0 = __builtin_amdgcn_mfma_f32_16x16x32_bf16(a, bfrag[1][0], acc0, 0, 0, 0);
        acc1 = __builtin_amdgcn_mfma_f32_16x16x32_bf16(a, bfrag[1][1], acc1, 0, 0, 0);
        a = *(const bf16x8v*)&a1_s[bm + d2];
        acc0 = __builtin_amdgcn_mfma_f32_16x16x32_bf16(a, bfrag[2][0], acc0, 0, 0, 0);
        acc1 = __builtin_amdgcn_mfma_f32_16x16x32_bf16(a, bfrag[2][1], acc1, 0, 0, 0);
        a = *(const bf16x8v*)&a1_s[bm + d3];
        acc0 = __builtin_amdgcn_mfma_f32_16x16x32_bf16(a, bfrag[3][0], acc0, 0, 0, 0);
        acc1 = __builtin_amdgcn_mfma_f32_16x16x32_bf16(a, bfrag[3][1], acc1, 0, 0, 0);
        a = *(const bf16x8v*)&a1_s[fqh ? (ab + A1_ZS) : (bm + 672 + icb)];
        acc0 = __builtin_amdgcn_mfma_f32_16x16x32_bf16(a, bfrag[4][0], acc0, 0, 0, 0);
        acc1 = __builtin_amdgcn_mfma_f32_16x16x32_bf16(a, bfrag[4][1], acc1, 0, 0, 0);

        bf16x8v ov;
#pragma unroll
        for (int j = 0; j < 4; ++j) {
            bool valid = (m * 16 + fq * 4 + j) < 110;
            float v0 = valid ? fminf(fmaxf(acc0[j], 0.f), 1.f) : 0.f;
            float v1 = valid ? fminf(fmaxf(acc1[j], 0.f), 1.f) : 0.f;
            ov[j]     = (__bf16)v0;
            ov[4 + j] = (__bf16)v1;
        }
        *(bf16x8v*)&a2p[(size_t)(t * 2048 + b) * FC3_K + m * 512 + lane * 8] = ov;
    }
}

// ---------------- fc3: one GEMM [20480 x 3584] * [3584 x 256] (R8) --------
// 128x64 tile, 4 waves, BK=64, 56 K-steps, static x2 double buffer, depth-2
// prefetch (12 loads in flight, vmcnt(6)), hoisted pointers. XCD remap.
__global__ __launch_bounds__(256) void fc3_all_k(
    const __hip_bfloat16* __restrict__ A,   // [20480][3584]
    const __hip_bfloat16* __restrict__ W,   // [256][3584]
    __hip_bfloat16* __restrict__ a3)        // [20480][256]
{
    __shared__ __hip_bfloat16 As[2 * 128 * 64];
    __shared__ __hip_bfloat16 Bs[2 * 64 * 64];

    const int tid  = threadIdx.x;
    const int wv   = tid >> 6;
    const int lane = tid & 63;

    const int d    = blockIdx.x;            // 0..639
    const int xcd  = d & 7;
    const int slot = d >> 3;                // 0..79 within XCD
    const int n0   = (slot & 3) * 64;
    const int m0   = (xcd * 20 + (slot >> 2)) * 128;

    const int wr = wv >> 1, wc = wv & 1;

    const int srow   = lane >> 3;
    const int schunk = lane & 7;
    const int swzc   = schunk ^ srow;

    const int fr = lane & 15;
    const int fq = lane >> 4;

    const __hip_bfloat16* gA0 = A + (size_t)(m0 + wv * 32 +  0 + srow) * FC3_K + swzc * 8;
    const __hip_bfloat16* gA1 = A + (size_t)(m0 + wv * 32 +  8 + srow) * FC3_K + swzc * 8;
    const __hip_bfloat16* gA2 = A + (size_t)(m0 + wv * 32 + 16 + srow) * FC3_K + swzc * 8;
    const __hip_bfloat16* gA3 = A + (size_t)(m0 + wv * 32 + 24 + srow) * FC3_K + swzc * 8;
    const __hip_bfloat16* gB0 = W + (size_t)(n0 + wv * 16 +  0 + srow) * FC3_K + swzc * 8;
    const __hip_bfloat16* gB1 = W + (size_t)(n0 + wv * 16 +  8 + srow) * FC3_K + swzc * 8;

    __hip_bfloat16* ldsA0 = &As[(wv * 32 +  0) * 64];
    __hip_bfloat16* ldsA1 = &As[(wv * 32 +  8) * 64];
    __hip_bfloat16* ldsA2 = &As[(wv * 32 + 16) * 64];
    __hip_bfloat16* ldsA3 = &As[(wv * 32 + 24) * 64];
    __hip_bfloat16* ldsB0 = &Bs[(wv * 16 +  0) * 64];
    __hip_bfloat16* ldsB1 = &Bs[(wv * 16 +  8) * 64];

#define GLD(src, dst, boff)                                                   \
    __builtin_amdgcn_global_load_lds(                                          \
        (const __attribute__((address_space(1))) void*)(src),                  \
        (__attribute__((address_space(3))) void*)((dst) + (boff)), 16, 0, 0)

#define STAGE(b)                                                               \
    do {                                                                       \
        GLD(gA0, ldsA0, (b) * 8192); GLD(gA1, ldsA1, (b) * 8192);              \
        GLD(gA2, ldsA2, (b) * 8192); GLD(gA3, ldsA3, (b) * 8192);              \
        GLD(gB0, ldsB0, (b) * 4096); GLD(gB1, ldsB1, (b) * 4096);              \
        gA0 += 64; gA1 += 64; gA2 += 64; gA3 += 64; gB0 += 64; gB1 += 64;      \
    } while (0)

    int aofs[2][4], bofs[2][2];
#pragma unroll
    for (int kk = 0; kk < 2; ++kk) {
#pragma unroll
        for (int mi = 0; mi < 4; ++mi) {
            const int rr = wr * 64 + mi * 16 + fr;
            aofs[kk][mi] = rr * 64 + (((kk * 4 + fq) ^ (rr & 7)) * 8);
        }
#pragma unroll
        for (int ni = 0; ni < 2; ++ni) {
            const int rr = wc * 32 + ni * 16 + fr;
            bofs[kk][ni] = rr * 64 + (((kk * 4 + fq) ^ (rr & 7)) * 8);
        }
    }

    f32x4 acc[4][2];
#pragma unroll
    for (int mi = 0; mi < 4; ++mi)
#pragma unroll
        for (int ni = 0; ni < 2; ++ni)
            acc[mi][ni] = (f32x4){0.f, 0.f, 0.f, 0.f};

#define COMPUTE(b)                                                             \
    do {                                                                       \
        const __hip_bfloat16* Ab = &As[(b) * 8192];                            \
        const __hip_bfloat16* Bb = &Bs[(b) * 4096];                            \
        _Pragma("unroll")                                                      \
        for (int kk = 0; kk < 2; ++kk) {                                       \
            bf16x8v af[4], bfv[2];                                             \
            _Pragma("unroll")                                                  \
            for (int mi = 0; mi < 4; ++mi)                                     \
                af[mi] = *(const bf16x8v*)&Ab[aofs[kk][mi]];                   \
            _Pragma("unroll")                                                  \
            for (int ni = 0; ni < 2; ++ni)                                     \
                bfv[ni] = *(const bf16x8v*)&Bb[bofs[kk][ni]];                  \
            _Pragma("unroll")                                                  \
            for (int mi = 0; mi < 4; ++mi)                                     \
                _Pragma("unroll")                                              \
                for (int ni = 0; ni < 2; ++ni)                                 \
                    acc[mi][ni] = __builtin_amdgcn_mfma_f32_16x16x32_bf16(     \
                        af[mi], bfv[ni], acc[mi][ni], 0, 0, 0);                \
        }                                                                      \
    } while (0)

    STAGE(0);                     // kt 0 -> buf0
    STAGE(1);                     // kt 1 -> buf1   (12 loads in flight)

    for (int it = 0; it < 27; ++it) {
        WAITV(6);
        __builtin_amdgcn_s_barrier();
        COMPUTE(0);
        __builtin_amdgcn_s_barrier();
        STAGE(0);
        WAITV(6);
        __builtin_amdgcn_s_barrier();
        COMPUTE(1);
        __builtin_amdgcn_s_barrier();
        STAGE(1);
    }
    WAITV(6);
    __builtin_amdgcn_s_barrier();
    COMPUTE(0);
    WAITV(0);
    __builtin_amdgcn_s_barrier();
    COMPUTE(1);

#undef GLD
#undef STAGE
#undef COMPUTE

#pragma unroll
    for (int mi = 0; mi < 4; ++mi)
#pragma unroll
        for (int ni = 0; ni < 2; ++ni)
#pragma unroll
            for (int j = 0; j < 4; ++j) {
                int row = m0 + wr * 64 + mi * 16 + fq * 4 + j;
                int col = n0 + wc * 32 + ni * 16 + fr;
                float v = fminf(fmaxf(acc[mi][ni][j], 0.f), 1.f);
                a3[(size_t)row * 256 + col] = __float2bfloat16(v);
            }
}

// ---------------- MGU all steps + fc5, one kernel (R8) ----------------
__global__ __launch_bounds__(256, 1) void mgu_all_k(
    const __hip_bfloat16* __restrict__ a3,  // [10*2048][256]
    const __hip_bfloat16* __restrict__ wfi, const __hip_bfloat16* __restrict__ wfh,
    const float* __restrict__ w5, float* __restrict__ out)
{
    __shared__ __hip_bfloat16 a3_s[16 * 256];
    __shared__ __hip_bfloat16 hq_s[16 * 64];
    __shared__ float hx_s[16 * 64];
    __shared__ float w5_s[7 * 64];

    const int tid = threadIdx.x;
    const int wv  = tid >> 6, lane = tid & 63;
    const int fr  = lane & 15, fq = lane >> 4;
    const int b0  = blockIdx.x * 16;
    const int ntf = wv, ntn = wv + 4;

    bf16x8v wiF[8][2], wiN[8][2], whF[2][2], whN[2][2];
#pragma unroll
    for (int kt = 0; kt < 8; ++kt)
#pragma unroll
        for (int hl = 0; hl < 2; ++hl) {
            wiF[kt][hl] = *(const bf16x8v*)&wfi[(((ntf * 8 + kt) * 2 + hl) * 64 + lane) * 8];
            wiN[kt][hl] = *(const bf16x8v*)&wfi[(((ntn * 8 + kt) * 2 + hl) * 64 + lane) * 8];
        }
#pragma unroll
    for (int kt = 0; kt < 2; ++kt)
#pragma unroll
        for (int hl = 0; hl < 2; ++hl) {
            whF[kt][hl] = *(const bf16x8v*)&wfh[(((ntf * 2 + kt) * 2 + hl) * 64 + lane) * 8];
            whN[kt][hl] = *(const bf16x8v*)&wfh[(((ntn * 2 + kt) * 2 + hl) * 64 + lane) * 8];
        }

    for (int i = tid; i < 16 * 64; i += 256) hx_s[i] = 0.f;
    for (int i = tid; i < 7 * 64; i += 256) w5_s[i] = w5[i];
    __syncthreads();

    for (int t = 0; t < 10; ++t) {
#pragma unroll
        for (int pass = 0; pass < 2; ++pass) {
            int i = pass * 256 + tid;
            int r = i >> 5, cq = i & 31;
            bf16x8v v = *(const bf16x8v*)&a3[((size_t)(t * 2048 + b0 + r)) * 256 + cq * 8];
            *(bf16x8v*)&a3_s[r * 256 + ((cq ^ (r & 7)) * 8)] = v;
        }
#pragma unroll
        for (int pass = 0; pass < 4; ++pass) {
            int i = pass * 256 + tid;
            int r = i >> 6, c = i & 63;
            float v = hx_s[r * 64 + c];
            v = fminf(fmaxf(v, -1.f), 1.f);
            v = rintf(v * 128.f) * 0.0078125f;
            hq_s[r * 64 + (((c >> 3) ^ (r & 7)) << 3) + (c & 7)] = __float2bfloat16(v);
        }
        __syncthreads();

        f32x4 accF  = {0.f, 0.f, 0.f, 0.f};
        f32x4 accNi = {0.f, 0.f, 0.f, 0.f};
        f32x4 accNh = {0.f, 0.f, 0.f, 0.f};
#pragma unroll
        for (int kt = 0; kt < 8; ++kt) {
            bf16x8v a = *(const bf16x8v*)&a3_s[fr * 256 + (((kt * 4 + fq) ^ (fr & 7)) * 8)];
            accF  = __builtin_amdgcn_mfma_f32_16x16x32_bf16(a, wiF[kt][0], accF, 0, 0, 0);
            accF  = __builtin_amdgcn_mfma_f32_16x16x32_bf16(a, wiF[kt][1], accF, 0, 0, 0);
            accNi = __builtin_amdgcn_mfma_f32_16x16x32_bf16(a, wiN[kt][0], accNi, 0, 0, 0);
            accNi = __builtin_amdgcn_mfma_f32_16x16x32_bf16(a, wiN[kt][1], accNi, 0, 0, 0);
        }
#pragma unroll
        for (int kt = 0; kt < 2; ++kt) {
            bf16x8v a = *(const bf16x8v*)&hq_s[fr * 64 + (((kt * 4 + fq) ^ (fr & 7)) * 8)];
            accF  = __builtin_amdgcn_mfma_f32_16x16x32_bf16(a, whF[kt][0], accF, 0, 0, 0);
            accF  = __builtin_amdgcn_mfma_f32_16x16x32_bf16(a, whF[kt][1], accF, 0, 0, 0);
            accNh = __builtin_amdgcn_mfma_f32_16x16x32_bf16(a, whN[kt][0], accNh, 0, 0, 0);
            accNh = __builtin_amdgcn_mfma_f32_16x16x32_bf16(a, whN[kt][1], accNh, 0, 0, 0);
        }

        const int j5 = wv * 16 + fr;
#pragma unroll
        for (int j = 0; j < 4; ++j) {
            int b = fq * 4 + j;
            float f = fminf(fmaxf(0.5f * accF[j] + 0.5f, 0.f), 1.f);
            float n = fminf(fmaxf(accNi[j] + f * accNh[j], -1.f), 1.f);
            float hq = __bfloat162float(
                hq_s[b * 64 + ((((j5) >> 3) ^ (b & 7)) << 3) + (j5 & 7)]);
            hx_s[b * 64 + j5] = (1.f - f) * n + f * hq;
        }
        __syncthreads();
    }

    if (tid < 112) {
        int b = tid / 7, c = tid % 7;
        float acc = 0.f;
#pragma unroll
        for (int k = 0; k < 64; ++k) acc += hx_s[b * 64 + k] * w5_s[c * 64 + k];
        out[(size_t)(b0 + b) * 7 + c] = acc;
    }
}

extern "C" void kernel_launch(void* const* d_in, const int* in_sizes, int n_in,
                              void* d_out, int out_size, void* d_ws, size_t ws_size,
                              hipStream_t stream)
{
    const float* x    = (const float*)d_in[0];
    const float* w1   = (const float*)d_in[1];
    const float* w2   = (const float*)d_in[2];
    const float* fc3w = (const float*)d_in[3];
    const float* wih  = (const float*)d_in[4];
    const float* whh  = (const float*)d_in[5];
    const float* fc5w = (const float*)d_in[6];
    float* out = (float*)d_out;

    char* ws = (char*)d_ws;
    __hip_bfloat16* a2p = (__hip_bfloat16*)ws;                     // 146,800,640
    __hip_bfloat16* a3  = (__hip_bfloat16*)(ws + 146800640);       //  10,485,760
    __hip_bfloat16* w3p = (__hip_bfloat16*)(ws + 157286400);       //   1,835,008
    __hip_bfloat16* w2p = (__hip_bfloat16*)(ws + 159121408);       //      10,240
    __hip_bfloat16* wfi = (__hip_bfloat16*)(ws + 159131648);       //     131,072
    __hip_bfloat16* wfh = (__hip_bfloat16*)(ws + 159262720);       //      32,768

    cvt_all_k<<<981, 256, 0, stream>>>(fc3w, w2, wih, whh, w3p, w2p, wfi, wfh);
    conv_all_k<<<5120, 256, 0, stream>>>(x, w1, w2p, a2p);
    fc3_all_k<<<640, 256, 0, stream>>>(a2p, w3p, a3);
    mgu_all_k<<<128, 256, 0, stream>>>(a3, wfi, wfh, fc5w, out);
}